// Round 2
// baseline (6450.680 us; speedup 1.0000x reference)
//
#include <hip/hip_runtime.h>
#include <stdint.h>

#define N_TOTAL 21840
#define NA      21888          // N_TOTAL rounded up to multiple of 64
#define W_MAX   342            // ceil(21840/64)
#define NMS_TH  0.3f
#define FINAL_TH 0.5f

struct Inputs { const float* cls[6]; const float* reg[6]; };

// ---------------------------------------------------------------- decode ----
__global__ void decode_kernel(Inputs in,
                              float* __restrict__ dx1, float* __restrict__ dy1,
                              float* __restrict__ dx2, float* __restrict__ dy2,
                              float* __restrict__ dsc,
                              unsigned long long* __restrict__ ckey,
                              unsigned int* __restrict__ Mc) {
#pragma clang fp contract(off)
  int gid = blockIdx.x * blockDim.x + threadIdx.x;
  if (gid >= N_TOTAL) return;

  int sc, local;
  if      (gid < 16384) { sc = 0; local = gid;         }
  else if (gid < 20480) { sc = 1; local = gid - 16384; }
  else if (gid < 21504) { sc = 2; local = gid - 20480; }
  else if (gid < 21760) { sc = 3; local = gid - 21504; }
  else if (gid < 21824) { sc = 4; local = gid - 21760; }
  else                  { sc = 5; local = gid - 21824; }

  const int Wd     = 128 >> sc;          // map width
  const int stride = 4 << sc;
  const int HW     = Wd * Wd;
  const int x = local & (Wd - 1);
  const int y = local >> (7 - sc);

  const float* cls = in.cls[sc];
  const float* reg = in.reg[sc];

  float c0 = cls[local];
  float c1 = cls[HW + local];
  // jax.nn.softmax: subtract max, exp, normalize -> prob of channel 1
  float m  = fmaxf(c0, c1);
  float e0 = expf(c0 - m);
  float e1 = expf(c1 - m);
  float prob = e1 / (e0 + e1);

  float l0 = reg[local];
  float l1 = reg[HW + local];
  float l2 = reg[2 * HW + local];
  float l3 = reg[3 * HW + local];

  float sF  = (float)stride;
  float pcx = 0.5f * sF + (float)x * sF;
  float pcy = 0.5f * sF + (float)y * sF;
  float pwh = sF * 4.0f;

  float cx = pcx + ((l0 * 0.1f) * pwh);
  float cy = pcy + ((l1 * 0.1f) * pwh);
  float w  = pwh * expf(l2 * 0.2f);
  float h  = pwh * expf(l3 * 0.2f);
  float x1 = cx - w * 0.5f;   // ref: cx - w/2  (w/2 == w*0.5 exactly)
  float y1 = cy - h * 0.5f;
  float x2 = x1 + w;
  float y2 = y1 + h;

  dx1[gid] = x1; dy1[gid] = y1; dx2[gid] = x2; dy2[gid] = y2; dsc[gid] = prob;

  // Only boxes with score > FINAL_TH can affect the output (suppression only
  // flows downward in score order) -> compact candidates.
  if (prob > FINAL_TH) {
    unsigned int pos = atomicAdd(Mc, 1u);
    // key: descending score, tie -> ascending original index (stable argsort(-s))
    ckey[pos] = ((unsigned long long)__float_as_uint(prob) << 32) |
                (unsigned int)(~(unsigned int)gid);
  }
}

// ---------------------------------------------------------------- rank ------
// Sort-by-counting: rank_p = #{q : key_q > key_p}; scatter boxes into sorted SoA.
__global__ void rank_kernel(const unsigned long long* __restrict__ ckey,
                            const unsigned int* __restrict__ Mc,
                            const float* __restrict__ dx1, const float* __restrict__ dy1,
                            const float* __restrict__ dx2, const float* __restrict__ dy2,
                            float* __restrict__ sx1, float* __restrict__ sy1,
                            float* __restrict__ sx2, float* __restrict__ sy2,
                            unsigned int* __restrict__ sorig) {
  __shared__ unsigned long long tile[256];
  unsigned int M = *Mc;
  if (blockIdx.x * 256u >= M) return;            // uniform per block
  int p = blockIdx.x * 256 + threadIdx.x;
  unsigned long long mykey = (p < (int)M) ? ckey[p] : 0ull;
  int rank = 0;
  int ntiles = (int)((M + 255u) >> 8);
  for (int t = 0; t < ntiles; ++t) {
    int j = t * 256 + threadIdx.x;
    tile[threadIdx.x] = (j < (int)M) ? ckey[j] : 0ull;
    __syncthreads();
    if (p < (int)M) {
#pragma unroll 8
      for (int q = 0; q < 256; ++q) rank += (tile[q] > mykey) ? 1 : 0;
    }
    __syncthreads();
  }
  if (p < (int)M) {
    unsigned int orig = ~(unsigned int)(mykey & 0xffffffffull);
    sx1[rank] = dx1[orig];
    sy1[rank] = dy1[orig];
    sx2[rank] = dx2[orig];
    sy2[rank] = dy2[orig];
    sorig[rank] = orig;
  }
}

// ---------------------------------------------------------------- NMS -------
// Single-block word-batched greedy NMS over sorted candidates.
__global__ void __launch_bounds__(1024)
nms_kernel(const float* __restrict__ sx1, const float* __restrict__ sy1,
           const float* __restrict__ sx2, const float* __restrict__ sy2,
           const unsigned int* __restrict__ sorig,
           const unsigned int* __restrict__ Mc,
           unsigned int* __restrict__ keepflag) {
#pragma clang fp contract(off)
  __shared__ unsigned long long sup[W_MAX];   // suppressed bits, by sorted pos
  __shared__ unsigned long long inrow[64];    // in-word 64x64 IoU block (c>r bits)
  __shared__ float wx1[64], wy1[64], wx2[64], wy2[64], warea[64];
  __shared__ unsigned long long keptmask_sh;

  const int t = (int)threadIdx.x;
  const int M = (int)*Mc;
  const int W = (M + 63) >> 6;

  for (int i = t; i < W_MAX; i += 1024) sup[i] = 0ull;
  __syncthreads();

  for (int w = 0; w < W; ++w) {
    const int base = w << 6;
    const int n = min(64, M - base);

    // stage this word's boxes + clear inrow
    if (t < 64) {
      if (t < n) {
        float a = sx1[base + t], b = sy1[base + t];
        float c = sx2[base + t], d = sy2[base + t];
        wx1[t] = a; wy1[t] = b; wx2[t] = c; wy2[t] = d;
        warea[t] = (c - a + 1.0f) * (d - b + 1.0f);
      }
    } else if (t < 128) {
      inrow[t - 64] = 0ull;
    }
    __syncthreads();

    // fill 64x64 in-word suppression block: thread -> (row r, 4-col segment)
    {
      int r = t & 63;
      int seg = t >> 6;
      unsigned long long bits = 0ull;
      if (r < n) {
        float ax1 = wx1[r], ay1 = wy1[r], ax2 = wx2[r], ay2 = wy2[r];
        float aarea = warea[r];
        int c0 = seg * 4;
        for (int c = c0; c < c0 + 4; ++c) {
          if (c > r && c < n) {
            float xx1 = fmaxf(ax1, wx1[c]);
            float yy1 = fmaxf(ay1, wy1[c]);
            float xx2 = fminf(ax2, wx2[c]);
            float yy2 = fminf(ay2, wy2[c]);
            float ww = fmaxf(xx2 - xx1 + 1.0f, 0.0f);
            float hh = fmaxf(yy2 - yy1 + 1.0f, 0.0f);
            float inter = ww * hh;
            float iou = inter / (aarea + warea[c] - inter);
            if (iou > NMS_TH) bits |= (1ull << c);
          }
        }
      }
      if (bits) atomicOr(&inrow[r], bits);
    }
    __syncthreads();

    // serial greedy scan within the word (wave 0, redundant-uniform loop)
    if (t < 64) {
      unsigned long long wordmask = (n >= 64) ? ~0ull : ((1ull << n) - 1ull);
      unsigned long long pending = (~sup[w]) & wordmask;
      unsigned long long kept = 0ull;
      while (pending) {
        int i = __builtin_ctzll(pending);
        kept |= (1ull << i);
        pending &= ~(inrow[i] | (1ull << i));
      }
      if (t == 0) keptmask_sh = kept;
      if (t < n && ((kept >> t) & 1ull)) keepflag[sorig[base + t]] = 1u;
    }
    __syncthreads();

    // suppress all later words against this word's kept boxes
    unsigned long long km = keptmask_sh;
    if (km) {
      int wid = t >> 6, lane = t & 63;
      for (int jw = w + 1 + wid; (jw << 6) < M; jw += 16) {
        int j = (jw << 6) + lane;
        bool supj = false;
        if (j < M) {
          float jx1 = sx1[j], jy1 = sy1[j], jx2 = sx2[j], jy2 = sy2[j];
          float jarea = (jx2 - jx1 + 1.0f) * (jy2 - jy1 + 1.0f);
          unsigned long long mm = km;
          while (mm) {
            int r = __builtin_ctzll(mm);
            mm &= mm - 1ull;
            float xx1 = fmaxf(wx1[r], jx1);
            float yy1 = fmaxf(wy1[r], jy1);
            float xx2 = fminf(wx2[r], jx2);
            float yy2 = fminf(wy2[r], jy2);
            float ww = fmaxf(xx2 - xx1 + 1.0f, 0.0f);
            float hh = fmaxf(yy2 - yy1 + 1.0f, 0.0f);
            float inter = ww * hh;
            float iou = inter / (warea[r] + jarea - inter);
            if (iou > NMS_TH) { supj = true; break; }
          }
        }
        unsigned long long bal = __ballot(supj);
        if (lane == 0 && bal) atomicOr(&sup[jw], bal);
      }
    }
    __syncthreads();
  }
}

// ---------------------------------------------------------------- output ----
__global__ void output_kernel(const float* __restrict__ dx1, const float* __restrict__ dy1,
                              const float* __restrict__ dx2, const float* __restrict__ dy2,
                              const float* __restrict__ dsc,
                              const unsigned int* __restrict__ keepflag,
                              float* __restrict__ out) {
#pragma clang fp contract(off)
  int gid = blockIdx.x * blockDim.x + threadIdx.x;
  if (gid >= N_TOTAL) return;
  float f = keepflag[gid] ? 1.0f : 0.0f;
  out[gid * 5 + 0] = dx1[gid] * f;
  out[gid * 5 + 1] = dy1[gid] * f;
  out[gid * 5 + 2] = dx2[gid] * f;
  out[gid * 5 + 3] = dy2[gid] * f;
  out[gid * 5 + 4] = dsc[gid] * f;
}

// ---------------------------------------------------------------- launch ----
extern "C" void kernel_launch(void* const* d_in, const int* in_sizes, int n_in,
                              void* d_out, int out_size, void* d_ws, size_t ws_size,
                              hipStream_t stream) {
  (void)in_sizes; (void)n_in; (void)out_size; (void)ws_size;

  Inputs in;
  for (int i = 0; i < 6; ++i) {
    in.cls[i] = (const float*)d_in[2 * i];
    in.reg[i] = (const float*)d_in[2 * i + 1];
  }

  char* ws = (char*)d_ws;
  size_t o = 0;
  float* dx1 = (float*)(ws + o); o += (size_t)NA * 4;
  float* dy1 = (float*)(ws + o); o += (size_t)NA * 4;
  float* dx2 = (float*)(ws + o); o += (size_t)NA * 4;
  float* dy2 = (float*)(ws + o); o += (size_t)NA * 4;
  float* dsc = (float*)(ws + o); o += (size_t)NA * 4;
  unsigned long long* ckey = (unsigned long long*)(ws + o); o += (size_t)NA * 8;
  float* sx1 = (float*)(ws + o); o += (size_t)NA * 4;
  float* sy1 = (float*)(ws + o); o += (size_t)NA * 4;
  float* sx2 = (float*)(ws + o); o += (size_t)NA * 4;
  float* sy2 = (float*)(ws + o); o += (size_t)NA * 4;
  unsigned int* sorig = (unsigned int*)(ws + o); o += (size_t)NA * 4;
  unsigned int* keepflag = (unsigned int*)(ws + o); o += (size_t)NA * 4;
  unsigned int* Mc = (unsigned int*)(ws + o); o += 64;

  // zero keepflag + Mc in one memset (contiguous)
  (void)hipMemsetAsync((void*)keepflag, 0, (size_t)NA * 4 + 64, stream);

  const int nb = (N_TOTAL + 255) / 256;  // 86
  decode_kernel<<<nb, 256, 0, stream>>>(in, dx1, dy1, dx2, dy2, dsc, ckey, Mc);
  rank_kernel<<<nb, 256, 0, stream>>>(ckey, Mc, dx1, dy1, dx2, dy2,
                                      sx1, sy1, sx2, sy2, sorig);
  nms_kernel<<<1, 1024, 0, stream>>>(sx1, sy1, sx2, sy2, sorig, Mc, keepflag);
  output_kernel<<<nb, 256, 0, stream>>>(dx1, dy1, dx2, dy2, dsc, keepflag, (float*)d_out);
}

// Round 3
// 790.542 us; speedup vs baseline: 8.1598x; 8.1598x over previous
//
#include <hip/hip_runtime.h>
#include <stdint.h>

#define N_TOTAL 21840
#define NA      21888          // N_TOTAL rounded up to multiple of 64
#define W_MAX   342            // ceil(21840/64)
#define NMS_TH  0.3f
#define FINAL_TH 0.5f

struct Inputs { const float* cls[6]; const float* reg[6]; };

// ---------------------------------------------------------------- decode ----
__global__ void decode_kernel(Inputs in,
                              float* __restrict__ dx1, float* __restrict__ dy1,
                              float* __restrict__ dx2, float* __restrict__ dy2,
                              float* __restrict__ dsc,
                              unsigned long long* __restrict__ ckey,
                              unsigned int* __restrict__ Mc) {
#pragma clang fp contract(off)
  int gid = blockIdx.x * blockDim.x + threadIdx.x;
  if (gid >= N_TOTAL) return;

  int sc, local;
  if      (gid < 16384) { sc = 0; local = gid;         }
  else if (gid < 20480) { sc = 1; local = gid - 16384; }
  else if (gid < 21504) { sc = 2; local = gid - 20480; }
  else if (gid < 21760) { sc = 3; local = gid - 21504; }
  else if (gid < 21824) { sc = 4; local = gid - 21760; }
  else                  { sc = 5; local = gid - 21824; }

  const int Wd     = 128 >> sc;          // map width
  const int stride = 4 << sc;
  const int HW     = Wd * Wd;
  const int x = local & (Wd - 1);
  const int y = local >> (7 - sc);

  const float* cls = in.cls[sc];
  const float* reg = in.reg[sc];

  float c0 = cls[local];
  float c1 = cls[HW + local];
  float m  = fmaxf(c0, c1);
  float e0 = expf(c0 - m);
  float e1 = expf(c1 - m);
  float prob = e1 / (e0 + e1);

  float l0 = reg[local];
  float l1 = reg[HW + local];
  float l2 = reg[2 * HW + local];
  float l3 = reg[3 * HW + local];

  float sF  = (float)stride;
  float pcx = 0.5f * sF + (float)x * sF;
  float pcy = 0.5f * sF + (float)y * sF;
  float pwh = sF * 4.0f;

  float cx = pcx + ((l0 * 0.1f) * pwh);
  float cy = pcy + ((l1 * 0.1f) * pwh);
  float w  = pwh * expf(l2 * 0.2f);
  float h  = pwh * expf(l3 * 0.2f);
  float x1 = cx - w * 0.5f;
  float y1 = cy - h * 0.5f;
  float x2 = x1 + w;
  float y2 = y1 + h;

  dx1[gid] = x1; dy1[gid] = y1; dx2[gid] = x2; dy2[gid] = y2; dsc[gid] = prob;

  // Only boxes with score > FINAL_TH can affect the output (suppression only
  // flows downward in score order, and only >FINAL_TH rows are exposed).
  if (prob > FINAL_TH) {
    unsigned int pos = atomicAdd(Mc, 1u);
    ckey[pos] = ((unsigned long long)__float_as_uint(prob) << 32) |
                (unsigned int)(~(unsigned int)gid);
  }
}

// ---------------------------------------------------------------- rank ------
__global__ void rank_kernel(const unsigned long long* __restrict__ ckey,
                            const unsigned int* __restrict__ Mc,
                            const float* __restrict__ dx1, const float* __restrict__ dy1,
                            const float* __restrict__ dx2, const float* __restrict__ dy2,
                            float* __restrict__ sx1, float* __restrict__ sy1,
                            float* __restrict__ sx2, float* __restrict__ sy2,
                            unsigned int* __restrict__ sorig) {
  __shared__ unsigned long long tile[256];
  unsigned int M = *Mc;
  if (blockIdx.x * 256u >= M) return;
  int p = blockIdx.x * 256 + threadIdx.x;
  unsigned long long mykey = (p < (int)M) ? ckey[p] : 0ull;
  int rank = 0;
  int ntiles = (int)((M + 255u) >> 8);
  for (int t = 0; t < ntiles; ++t) {
    int j = t * 256 + threadIdx.x;
    tile[threadIdx.x] = (j < (int)M) ? ckey[j] : 0ull;
    __syncthreads();
    if (p < (int)M) {
#pragma unroll 8
      for (int q = 0; q < 256; ++q) rank += (tile[q] > mykey) ? 1 : 0;
    }
    __syncthreads();
  }
  if (p < (int)M) {
    unsigned int orig = ~(unsigned int)(mykey & 0xffffffffull);
    sx1[rank] = dx1[orig];
    sy1[rank] = dy1[orig];
    sx2[rank] = dx2[orig];
    sy2[rank] = dy2[orig];
    sorig[rank] = orig;
  }
}

// ---------------------------------------------------------------- pairs -----
// Whole-GPU suppression-matrix build. maskT[cw * NA + row] bit c set iff
// box (cw*64+c) is suppressed by box `row` (IoU > th, col > row).
// Transposed layout -> every global access is 64-lane coalesced.
__global__ void __launch_bounds__(256)
pairs_kernel(const float* __restrict__ sx1, const float* __restrict__ sy1,
             const float* __restrict__ sx2, const float* __restrict__ sy2,
             const unsigned int* __restrict__ Mc,
             unsigned long long* __restrict__ maskT) {
#pragma clang fp contract(off)
  const int M = (int)*Mc;
  const int W = (M + 63) >> 6;
  const int rw = (int)blockIdx.y;
  const int cw_base = (int)blockIdx.x << 2;
  if (rw >= W || cw_base >= W || cw_base + 3 < rw) return;

  const int t = (int)threadIdx.x;
  const int g = t >> 6, l = t & 63;
  const int cw = cw_base + g;                 // this wave's col-word

  __shared__ float cx1[256], cy1[256], cx2[256], cy2[256], car[256];
  {
    int c = (cw << 6) + l;
    if (cw < W && c < M) {
      float a = sx1[c], b = sy1[c], d = sx2[c], e = sy2[c];
      cx1[t] = a; cy1[t] = b; cx2[t] = d; cy2[t] = e;
      car[t] = (d - a + 1.0f) * (e - b + 1.0f);
    }
  }
  __syncthreads();
  if (cw >= W || cw < rw) return;             // no further barriers below

  const int r = (rw << 6) + l;
  unsigned long long bits = 0ull;
  if (r < M) {
    float ax1 = sx1[r], ay1 = sy1[r], ax2 = sx2[r], ay2 = sy2[r];
    float aarea = (ax2 - ax1 + 1.0f) * (ay2 - ay1 + 1.0f);
    const int cmax = min(64, M - (cw << 6));
    const int sb = g << 6;
    for (int cc = 0; cc < cmax; ++cc) {
      int cg = (cw << 6) + cc;
      if (cg > r) {
        float xx1 = fmaxf(ax1, cx1[sb + cc]);
        float yy1 = fmaxf(ay1, cy1[sb + cc]);
        float xx2 = fminf(ax2, cx2[sb + cc]);
        float yy2 = fminf(ay2, cy2[sb + cc]);
        float ww = fmaxf(xx2 - xx1 + 1.0f, 0.0f);
        float hh = fmaxf(yy2 - yy1 + 1.0f, 0.0f);
        float inter = ww * hh;
        float iou = inter / (aarea + car[sb + cc] - inter);
        if (iou > NMS_TH) bits |= (1ull << cc);
      }
    }
  }
  maskT[(size_t)cw * NA + r] = bits;          // coalesced: consecutive r per wave
}

// ---------------------------------------------------------------- scan ------
// Single-block greedy scan over the precomputed matrix: pure bit ops +
// coalesced row reads, no IoU recomputation.
__global__ void __launch_bounds__(1024)
scan_kernel(const unsigned long long* __restrict__ maskT,
            const unsigned int* __restrict__ sorig,
            const unsigned int* __restrict__ Mc,
            unsigned int* __restrict__ keepflag) {
  __shared__ unsigned long long sup[W_MAX];
  __shared__ unsigned long long keptmask_sh;
  const int t = (int)threadIdx.x;
  const int g = t >> 6, l = t & 63;
  const int M = (int)*Mc;
  const int W = (M + 63) >> 6;

  for (int i = t; i < W_MAX; i += 1024) sup[i] = 0ull;
  __syncthreads();

  for (int w = 0; w < W; ++w) {
    const int base = w << 6;
    if (g == 0) {
      const int row = base + l;
      unsigned long long rowbits = (row < M) ? maskT[(size_t)w * NA + row] : 0ull;
      unsigned long long nz = __ballot(rowbits != 0ull);   // rows w/ in-word bits
      const int n = min(64, M - base);
      unsigned long long wordmask = (n >= 64) ? ~0ull : ((1ull << n) - 1ull);
      unsigned long long pend = (~sup[w]) & wordmask;
      unsigned long long kept = 0ull;
      unsigned long long act = pend & nz;
      while (act) {                       // iterations = #kept rows w/ bits (~few)
        int i = __builtin_ctzll(act);
        unsigned long long upto = (2ull << i) - 1ull;  // bits [0..i] (i=63 -> ~0)
        kept |= pend & upto;              // quiet bits below i + i itself: kept
        unsigned long long ri = __shfl(rowbits, i);
        pend &= ~upto;
        pend &= ~ri;                      // suppress i's victims (all > i)
        act = pend & nz;
      }
      kept |= pend;                       // trailing quiet bits
      if (l == 0) keptmask_sh = kept;
      if (l < n && ((kept >> l) & 1ull)) keepflag[sorig[base + l]] = 1u;
    }
    __syncthreads();
    const unsigned long long km = keptmask_sh;
    if (km != 0ull) {
      const bool mine = ((km >> l) & 1ull) != 0ull;
      for (int jw = w + 1 + g; jw < W; jw += 16) {
        unsigned long long v = mine ? maskT[(size_t)jw * NA + base + l] : 0ull;
        if (v) atomicOr(&sup[jw], v);     // rare: most rows have no bits in jw
      }
    }
    __syncthreads();
  }
}

// ------------------------------------------------- fallback NMS (tiny ws) ---
__global__ void __launch_bounds__(1024)
nms_kernel(const float* __restrict__ sx1, const float* __restrict__ sy1,
           const float* __restrict__ sx2, const float* __restrict__ sy2,
           const unsigned int* __restrict__ sorig,
           const unsigned int* __restrict__ Mc,
           unsigned int* __restrict__ keepflag) {
#pragma clang fp contract(off)
  __shared__ unsigned long long sup[W_MAX];
  __shared__ unsigned long long inrow[64];
  __shared__ float wx1[64], wy1[64], wx2[64], wy2[64], warea[64];
  __shared__ unsigned long long keptmask_sh;

  const int t = (int)threadIdx.x;
  const int M = (int)*Mc;
  const int W = (M + 63) >> 6;

  for (int i = t; i < W_MAX; i += 1024) sup[i] = 0ull;
  __syncthreads();

  for (int w = 0; w < W; ++w) {
    const int base = w << 6;
    const int n = min(64, M - base);
    if (t < 64) {
      if (t < n) {
        float a = sx1[base + t], b = sy1[base + t];
        float c = sx2[base + t], d = sy2[base + t];
        wx1[t] = a; wy1[t] = b; wx2[t] = c; wy2[t] = d;
        warea[t] = (c - a + 1.0f) * (d - b + 1.0f);
      }
    } else if (t < 128) {
      inrow[t - 64] = 0ull;
    }
    __syncthreads();
    {
      int r = t & 63, seg = t >> 6;
      unsigned long long bits = 0ull;
      if (r < n) {
        float ax1 = wx1[r], ay1 = wy1[r], ax2 = wx2[r], ay2 = wy2[r];
        float aarea = warea[r];
        for (int c = seg * 4; c < seg * 4 + 4; ++c) {
          if (c > r && c < n) {
            float xx1 = fmaxf(ax1, wx1[c]);
            float yy1 = fmaxf(ay1, wy1[c]);
            float xx2 = fminf(ax2, wx2[c]);
            float yy2 = fminf(ay2, wy2[c]);
            float ww = fmaxf(xx2 - xx1 + 1.0f, 0.0f);
            float hh = fmaxf(yy2 - yy1 + 1.0f, 0.0f);
            float inter = ww * hh;
            float iou = inter / (aarea + warea[c] - inter);
            if (iou > NMS_TH) bits |= (1ull << c);
          }
        }
      }
      if (bits) atomicOr(&inrow[r], bits);
    }
    __syncthreads();
    if (t < 64) {
      unsigned long long wordmask = (n >= 64) ? ~0ull : ((1ull << n) - 1ull);
      unsigned long long pending = (~sup[w]) & wordmask;
      unsigned long long kept = 0ull;
      while (pending) {
        int i = __builtin_ctzll(pending);
        kept |= (1ull << i);
        pending &= ~(inrow[i] | (1ull << i));
      }
      if (t == 0) keptmask_sh = kept;
      if (t < n && ((kept >> t) & 1ull)) keepflag[sorig[base + t]] = 1u;
    }
    __syncthreads();
    unsigned long long km = keptmask_sh;
    if (km) {
      int wid = t >> 6, lane = t & 63;
      for (int jw = w + 1 + wid; (jw << 6) < M; jw += 16) {
        int j = (jw << 6) + lane;
        bool supj = false;
        if (j < M) {
          float jx1 = sx1[j], jy1 = sy1[j], jx2 = sx2[j], jy2 = sy2[j];
          float jarea = (jx2 - jx1 + 1.0f) * (jy2 - jy1 + 1.0f);
          unsigned long long mm = km;
          while (mm) {
            int r = __builtin_ctzll(mm);
            mm &= mm - 1ull;
            float xx1 = fmaxf(wx1[r], jx1);
            float yy1 = fmaxf(wy1[r], jy1);
            float xx2 = fminf(wx2[r], jx2);
            float yy2 = fminf(wy2[r], jy2);
            float ww = fmaxf(xx2 - xx1 + 1.0f, 0.0f);
            float hh = fmaxf(yy2 - yy1 + 1.0f, 0.0f);
            float inter = ww * hh;
            float iou = inter / (warea[r] + jarea - inter);
            if (iou > NMS_TH) { supj = true; break; }
          }
        }
        unsigned long long bal = __ballot(supj);
        if (lane == 0 && bal) atomicOr(&sup[jw], bal);
      }
    }
    __syncthreads();
  }
}

// ---------------------------------------------------------------- output ----
__global__ void output_kernel(const float* __restrict__ dx1, const float* __restrict__ dy1,
                              const float* __restrict__ dx2, const float* __restrict__ dy2,
                              const float* __restrict__ dsc,
                              const unsigned int* __restrict__ keepflag,
                              float* __restrict__ out) {
#pragma clang fp contract(off)
  int gid = blockIdx.x * blockDim.x + threadIdx.x;
  if (gid >= N_TOTAL) return;
  float f = keepflag[gid] ? 1.0f : 0.0f;
  out[gid * 5 + 0] = dx1[gid] * f;
  out[gid * 5 + 1] = dy1[gid] * f;
  out[gid * 5 + 2] = dx2[gid] * f;
  out[gid * 5 + 3] = dy2[gid] * f;
  out[gid * 5 + 4] = dsc[gid] * f;
}

// ---------------------------------------------------------------- launch ----
extern "C" void kernel_launch(void* const* d_in, const int* in_sizes, int n_in,
                              void* d_out, int out_size, void* d_ws, size_t ws_size,
                              hipStream_t stream) {
  (void)in_sizes; (void)n_in; (void)out_size;

  Inputs in;
  for (int i = 0; i < 6; ++i) {
    in.cls[i] = (const float*)d_in[2 * i];
    in.reg[i] = (const float*)d_in[2 * i + 1];
  }

  char* ws = (char*)d_ws;
  size_t o = 0;
  float* dx1 = (float*)(ws + o); o += (size_t)NA * 4;
  float* dy1 = (float*)(ws + o); o += (size_t)NA * 4;
  float* dx2 = (float*)(ws + o); o += (size_t)NA * 4;
  float* dy2 = (float*)(ws + o); o += (size_t)NA * 4;
  float* dsc = (float*)(ws + o); o += (size_t)NA * 4;
  unsigned long long* ckey = (unsigned long long*)(ws + o); o += (size_t)NA * 8;
  float* sx1 = (float*)(ws + o); o += (size_t)NA * 4;
  float* sy1 = (float*)(ws + o); o += (size_t)NA * 4;
  float* sx2 = (float*)(ws + o); o += (size_t)NA * 4;
  float* sy2 = (float*)(ws + o); o += (size_t)NA * 4;
  unsigned int* sorig = (unsigned int*)(ws + o); o += (size_t)NA * 4;
  unsigned int* keepflag = (unsigned int*)(ws + o); o += (size_t)NA * 4;
  unsigned int* Mc = (unsigned int*)(ws + o); o += 64;
  o = (o + 511) & ~(size_t)511;
  unsigned long long* maskT = (unsigned long long*)(ws + o);
  size_t need = o + (size_t)W_MAX * NA * 8;   // ~57 MiB
  const bool fast = (need <= ws_size);        // ws_size constant -> graph-safe

  (void)hipMemsetAsync((void*)keepflag, 0, (size_t)NA * 4 + 64, stream);

  const int nb = (N_TOTAL + 255) / 256;  // 86
  decode_kernel<<<nb, 256, 0, stream>>>(in, dx1, dy1, dx2, dy2, dsc, ckey, Mc);
  rank_kernel<<<nb, 256, 0, stream>>>(ckey, Mc, dx1, dy1, dx2, dy2,
                                      sx1, sy1, sx2, sy2, sorig);
  if (fast) {
    pairs_kernel<<<dim3(86, W_MAX), 256, 0, stream>>>(sx1, sy1, sx2, sy2, Mc, maskT);
    scan_kernel<<<1, 1024, 0, stream>>>(maskT, sorig, Mc, keepflag);
  } else {
    nms_kernel<<<1, 1024, 0, stream>>>(sx1, sy1, sx2, sy2, sorig, Mc, keepflag);
  }
  output_kernel<<<nb, 256, 0, stream>>>(dx1, dy1, dx2, dy2, dsc, keepflag, (float*)d_out);
}

// Round 4
// 514.415 us; speedup vs baseline: 12.5398x; 1.5368x over previous
//
#include <hip/hip_runtime.h>
#include <stdint.h>

#define N_TOTAL 21840
#define NA      21888          // N_TOTAL rounded up to multiple of 64
#define W_MAX   342            // ceil(21840/64)
#define NMS_TH  0.3f
#define FINAL_TH 0.5f

struct Inputs { const float* cls[6]; const float* reg[6]; };

// ---------------------------------------------------------------- decode ----
__global__ void decode_kernel(Inputs in,
                              float* __restrict__ dx1, float* __restrict__ dy1,
                              float* __restrict__ dx2, float* __restrict__ dy2,
                              float* __restrict__ dsc,
                              unsigned long long* __restrict__ ckey,
                              unsigned int* __restrict__ Mc,
                              float* __restrict__ out) {
#pragma clang fp contract(off)
  int gid = blockIdx.x * blockDim.x + threadIdx.x;
  if (gid >= N_TOTAL) return;

  int sc, local;
  if      (gid < 16384) { sc = 0; local = gid;         }
  else if (gid < 20480) { sc = 1; local = gid - 16384; }
  else if (gid < 21504) { sc = 2; local = gid - 20480; }
  else if (gid < 21760) { sc = 3; local = gid - 21504; }
  else if (gid < 21824) { sc = 4; local = gid - 21760; }
  else                  { sc = 5; local = gid - 21824; }

  const int Wd     = 128 >> sc;
  const int stride = 4 << sc;
  const int HW     = Wd * Wd;
  const int x = local & (Wd - 1);
  const int y = local >> (7 - sc);

  const float* cls = in.cls[sc];
  const float* reg = in.reg[sc];

  float c0 = cls[local];
  float c1 = cls[HW + local];
  float m  = fmaxf(c0, c1);
  float e0 = expf(c0 - m);
  float e1 = expf(c1 - m);
  float prob = e1 / (e0 + e1);

  float l0 = reg[local];
  float l1 = reg[HW + local];
  float l2 = reg[2 * HW + local];
  float l3 = reg[3 * HW + local];

  float sF  = (float)stride;
  float pcx = 0.5f * sF + (float)x * sF;
  float pcy = 0.5f * sF + (float)y * sF;
  float pwh = sF * 4.0f;

  float cx = pcx + ((l0 * 0.1f) * pwh);
  float cy = pcy + ((l1 * 0.1f) * pwh);
  float w  = pwh * expf(l2 * 0.2f);
  float h  = pwh * expf(l3 * 0.2f);
  float x1 = cx - w * 0.5f;
  float y1 = cy - h * 0.5f;
  float x2 = x1 + w;
  float y2 = y1 + h;

  dx1[gid] = x1; dy1[gid] = y1; dx2[gid] = x2; dy2[gid] = y2; dsc[gid] = prob;

  // zero the output row; scan_kernel scatters the kept rows afterwards
  out[gid * 5 + 0] = 0.0f;
  out[gid * 5 + 1] = 0.0f;
  out[gid * 5 + 2] = 0.0f;
  out[gid * 5 + 3] = 0.0f;
  out[gid * 5 + 4] = 0.0f;

  // Only boxes with score > FINAL_TH can affect the output (suppression only
  // flows downward in score order, and only >FINAL_TH rows are exposed).
  if (prob > FINAL_TH) {
    unsigned int pos = atomicAdd(Mc, 1u);
    ckey[pos] = ((unsigned long long)__float_as_uint(prob) << 32) |
                (unsigned int)(~(unsigned int)gid);
  }
}

// ---------------------------------------------------------------- rank ------
// 4-way split count-rank: 1024 threads = 4 groups x 256; group s counts its
// quarter of the tiles; LDS join; group 0 scatters.
__global__ void __launch_bounds__(1024)
rank_kernel(const unsigned long long* __restrict__ ckey,
            const unsigned int* __restrict__ Mc,
            const float* __restrict__ dx1, const float* __restrict__ dy1,
            const float* __restrict__ dx2, const float* __restrict__ dy2,
            float* __restrict__ sx1, float* __restrict__ sy1,
            float* __restrict__ sx2, float* __restrict__ sy2,
            unsigned int* __restrict__ sorig) {
  __shared__ unsigned long long tile[1024];
  __shared__ int psum[1024];
  const int t = (int)threadIdx.x;
  const int pl = t & 255, s = t >> 8;
  const unsigned int M = *Mc;
  if (blockIdx.x * 256u >= M) return;           // uniform per block
  const int p = (int)blockIdx.x * 256 + pl;
  unsigned long long mykey = (p < (int)M) ? ckey[p] : 0ull;
  const int ntiles = (int)((M + 255u) >> 8);
  const int ntq = (ntiles + 3) >> 2;
  int rank = 0;
  for (int q = 0; q < ntq; ++q) {
    int tt = s * ntq + q;
    int j = tt * 256 + pl;
    tile[t] = (tt < ntiles && j < (int)M) ? ckey[j] : 0ull;  // 0 never > mykey
    __syncthreads();
    const unsigned long long* tp = &tile[s << 8];
#pragma unroll 8
    for (int q2 = 0; q2 < 256; ++q2) rank += (tp[q2] > mykey) ? 1 : 0;
    __syncthreads();
  }
  psum[t] = rank;
  __syncthreads();
  if (s == 0 && p < (int)M) {
    int r = psum[pl] + psum[256 + pl] + psum[512 + pl] + psum[768 + pl];
    unsigned int orig = ~(unsigned int)(mykey & 0xffffffffull);
    sx1[r] = dx1[orig];
    sy1[r] = dy1[orig];
    sx2[r] = dx2[orig];
    sy2[r] = dy2[orig];
    sorig[r] = orig;
  }
}

// ---------------------------------------------------------------- pairs -----
// maskT[cw * NA + row] bit c set iff box (cw*64+c) is suppressed by `row`.
__global__ void __launch_bounds__(256)
pairs_kernel(const float* __restrict__ sx1, const float* __restrict__ sy1,
             const float* __restrict__ sx2, const float* __restrict__ sy2,
             const unsigned int* __restrict__ Mc,
             unsigned long long* __restrict__ maskT) {
#pragma clang fp contract(off)
  const int M = (int)*Mc;
  const int W = (M + 63) >> 6;
  const int rw = (int)blockIdx.y;
  const int cw_base = (int)blockIdx.x << 2;
  if (rw >= W || cw_base >= W || cw_base + 3 < rw) return;

  const int t = (int)threadIdx.x;
  const int g = t >> 6, l = t & 63;
  const int cw = cw_base + g;

  __shared__ float cx1[256], cy1[256], cx2[256], cy2[256], car[256];
  {
    int c = (cw << 6) + l;
    if (cw < W && c < M) {
      float a = sx1[c], b = sy1[c], d = sx2[c], e = sy2[c];
      cx1[t] = a; cy1[t] = b; cx2[t] = d; cy2[t] = e;
      car[t] = (d - a + 1.0f) * (e - b + 1.0f);
    }
  }
  __syncthreads();
  if (cw >= W || cw < rw) return;

  const int r = (rw << 6) + l;
  unsigned long long bits = 0ull;
  if (r < M) {
    float ax1 = sx1[r], ay1 = sy1[r], ax2 = sx2[r], ay2 = sy2[r];
    float aarea = (ax2 - ax1 + 1.0f) * (ay2 - ay1 + 1.0f);
    const int cmax = min(64, M - (cw << 6));
    const int sb = g << 6;
    for (int cc = 0; cc < cmax; ++cc) {
      int cg = (cw << 6) + cc;
      if (cg > r) {
        float xx1 = fmaxf(ax1, cx1[sb + cc]);
        float yy1 = fmaxf(ay1, cy1[sb + cc]);
        float xx2 = fminf(ax2, cx2[sb + cc]);
        float yy2 = fminf(ay2, cy2[sb + cc]);
        float ww = fmaxf(xx2 - xx1 + 1.0f, 0.0f);
        float hh = fmaxf(yy2 - yy1 + 1.0f, 0.0f);
        float inter = ww * hh;
        float iou = inter / (aarea + car[sb + cc] - inter);
        if (iou > NMS_TH) bits |= (1ull << cc);
      }
    }
  }
  maskT[(size_t)cw * NA + r] = bits;
}

// ---------------------------------------------------------------- scan ------
// Single-block greedy scan: prefetched row blocks, 8-wide batched cross push,
// kept masks staged in LDS, output scattered in a final parallel sweep.
__global__ void __launch_bounds__(1024)
scan_kernel(const unsigned long long* __restrict__ maskT,
            const unsigned int* __restrict__ sorig,
            const unsigned int* __restrict__ Mc,
            const float* __restrict__ dx1, const float* __restrict__ dy1,
            const float* __restrict__ dx2, const float* __restrict__ dy2,
            const float* __restrict__ dsc,
            float* __restrict__ out) {
  __shared__ unsigned long long sup[W_MAX];
  __shared__ unsigned long long kmask[W_MAX];
  __shared__ unsigned long long keptmask_sh;
  const int t = (int)threadIdx.x;
  const int g = t >> 6, l = t & 63;
  const int M = (int)*Mc;
  const int W = (M + 63) >> 6;

  for (int i = t; i < W_MAX; i += 1024) sup[i] = 0ull;
  __syncthreads();

  // wave 0 prefetches word 0's row block
  unsigned long long rb = 0ull;
  if (g == 0) rb = (l < M) ? maskT[l] : 0ull;

  for (int w = 0; w < W; ++w) {
    const int base = w << 6;
    if (g == 0) {
      unsigned long long rowbits = rb;
      {   // prefetch next word's rows one full step ahead
        int nr = base + 64 + l;
        rb = (w + 1 < W && nr < M) ? maskT[(size_t)(w + 1) * NA + nr] : 0ull;
      }
      unsigned long long nz = __ballot(rowbits != 0ull);
      const int n = min(64, M - base);
      unsigned long long wordmask = (n >= 64) ? ~0ull : ((1ull << n) - 1ull);
      unsigned long long pend = (~sup[w]) & wordmask;
      unsigned long long kept = 0ull;
      unsigned long long act = pend & nz;
      while (act) {                       // iterations = #kept rows w/ bits
        int i = __builtin_ctzll(act);
        unsigned long long upto = (2ull << i) - 1ull;  // bits [0..i]
        kept |= pend & upto;
        unsigned long long ri = __shfl(rowbits, i);
        pend &= ~upto;
        pend &= ~ri;
        act = pend & nz;
      }
      kept |= pend;
      if (l == 0) { keptmask_sh = kept; kmask[w] = kept; }
    }
    __syncthreads();
    const unsigned long long km = keptmask_sh;
    if (km != 0ull) {
      const bool mine = ((km >> l) & 1ull) != 0ull;
      const size_t rowoff = (size_t)(base + l);
      // 8-wide batch, stride 16 across waves: ~1 vmcnt wait per batch
      for (int jw0 = w + 1 + g; jw0 < W; jw0 += 128) {
        unsigned long long v[8];
#pragma unroll
        for (int k = 0; k < 8; ++k) {
          int jw = jw0 + (k << 4);
          v[k] = (mine && jw < W) ? maskT[(size_t)jw * NA + rowoff] : 0ull;
        }
#pragma unroll
        for (int k = 0; k < 8; ++k) {
          int jw = jw0 + (k << 4);
          if (v[k]) atomicOr(&sup[jw], v[k]);
        }
      }
    }
    __syncthreads();
  }

  // scatter kept rows into the (pre-zeroed) output
  for (int i = t; i < (W << 6); i += 1024) {
    if ((kmask[i >> 6] >> (i & 63)) & 1ull) {
      unsigned int orig = sorig[i];
      out[(size_t)orig * 5 + 0] = dx1[orig];
      out[(size_t)orig * 5 + 1] = dy1[orig];
      out[(size_t)orig * 5 + 2] = dx2[orig];
      out[(size_t)orig * 5 + 3] = dy2[orig];
      out[(size_t)orig * 5 + 4] = dsc[orig];
    }
  }
}

// ------------------------------------------------- fallback NMS (tiny ws) ---
__global__ void __launch_bounds__(1024)
nms_kernel(const float* __restrict__ sx1, const float* __restrict__ sy1,
           const float* __restrict__ sx2, const float* __restrict__ sy2,
           const unsigned int* __restrict__ sorig,
           const unsigned int* __restrict__ Mc,
           unsigned int* __restrict__ keepflag) {
#pragma clang fp contract(off)
  __shared__ unsigned long long sup[W_MAX];
  __shared__ unsigned long long inrow[64];
  __shared__ float wx1[64], wy1[64], wx2[64], wy2[64], warea[64];
  __shared__ unsigned long long keptmask_sh;

  const int t = (int)threadIdx.x;
  const int M = (int)*Mc;
  const int W = (M + 63) >> 6;

  for (int i = t; i < W_MAX; i += 1024) sup[i] = 0ull;
  __syncthreads();

  for (int w = 0; w < W; ++w) {
    const int base = w << 6;
    const int n = min(64, M - base);
    if (t < 64) {
      if (t < n) {
        float a = sx1[base + t], b = sy1[base + t];
        float c = sx2[base + t], d = sy2[base + t];
        wx1[t] = a; wy1[t] = b; wx2[t] = c; wy2[t] = d;
        warea[t] = (c - a + 1.0f) * (d - b + 1.0f);
      }
    } else if (t < 128) {
      inrow[t - 64] = 0ull;
    }
    __syncthreads();
    {
      int r = t & 63, seg = t >> 6;
      unsigned long long bits = 0ull;
      if (r < n) {
        float ax1 = wx1[r], ay1 = wy1[r], ax2 = wx2[r], ay2 = wy2[r];
        float aarea = warea[r];
        for (int c = seg * 4; c < seg * 4 + 4; ++c) {
          if (c > r && c < n) {
            float xx1 = fmaxf(ax1, wx1[c]);
            float yy1 = fmaxf(ay1, wy1[c]);
            float xx2 = fminf(ax2, wx2[c]);
            float yy2 = fminf(ay2, wy2[c]);
            float ww = fmaxf(xx2 - xx1 + 1.0f, 0.0f);
            float hh = fmaxf(yy2 - yy1 + 1.0f, 0.0f);
            float inter = ww * hh;
            float iou = inter / (aarea + warea[c] - inter);
            if (iou > NMS_TH) bits |= (1ull << c);
          }
        }
      }
      if (bits) atomicOr(&inrow[r], bits);
    }
    __syncthreads();
    if (t < 64) {
      unsigned long long wordmask = (n >= 64) ? ~0ull : ((1ull << n) - 1ull);
      unsigned long long pending = (~sup[w]) & wordmask;
      unsigned long long kept = 0ull;
      while (pending) {
        int i = __builtin_ctzll(pending);
        kept |= (1ull << i);
        pending &= ~(inrow[i] | (1ull << i));
      }
      if (t == 0) keptmask_sh = kept;
      if (t < n && ((kept >> t) & 1ull)) keepflag[sorig[base + t]] = 1u;
    }
    __syncthreads();
    unsigned long long km = keptmask_sh;
    if (km) {
      int wid = t >> 6, lane = t & 63;
      for (int jw = w + 1 + wid; (jw << 6) < M; jw += 16) {
        int j = (jw << 6) + lane;
        bool supj = false;
        if (j < M) {
          float jx1 = sx1[j], jy1 = sy1[j], jx2 = sx2[j], jy2 = sy2[j];
          float jarea = (jx2 - jx1 + 1.0f) * (jy2 - jy1 + 1.0f);
          unsigned long long mm = km;
          while (mm) {
            int r = __builtin_ctzll(mm);
            mm &= mm - 1ull;
            float xx1 = fmaxf(wx1[r], jx1);
            float yy1 = fmaxf(wy1[r], jy1);
            float xx2 = fminf(wx2[r], jx2);
            float yy2 = fminf(wy2[r], jy2);
            float ww = fmaxf(xx2 - xx1 + 1.0f, 0.0f);
            float hh = fmaxf(yy2 - yy1 + 1.0f, 0.0f);
            float inter = ww * hh;
            float iou = inter / (warea[r] + jarea - inter);
            if (iou > NMS_TH) { supj = true; break; }
          }
        }
        unsigned long long bal = __ballot(supj);
        if (lane == 0 && bal) atomicOr(&sup[jw], bal);
      }
    }
    __syncthreads();
  }
}

// ---------------------------------------------------------------- output ----
// (fallback path only)
__global__ void output_kernel(const float* __restrict__ dx1, const float* __restrict__ dy1,
                              const float* __restrict__ dx2, const float* __restrict__ dy2,
                              const float* __restrict__ dsc,
                              const unsigned int* __restrict__ keepflag,
                              float* __restrict__ out) {
#pragma clang fp contract(off)
  int gid = blockIdx.x * blockDim.x + threadIdx.x;
  if (gid >= N_TOTAL) return;
  float f = keepflag[gid] ? 1.0f : 0.0f;
  out[gid * 5 + 0] = dx1[gid] * f;
  out[gid * 5 + 1] = dy1[gid] * f;
  out[gid * 5 + 2] = dx2[gid] * f;
  out[gid * 5 + 3] = dy2[gid] * f;
  out[gid * 5 + 4] = dsc[gid] * f;
}

// ---------------------------------------------------------------- launch ----
extern "C" void kernel_launch(void* const* d_in, const int* in_sizes, int n_in,
                              void* d_out, int out_size, void* d_ws, size_t ws_size,
                              hipStream_t stream) {
  (void)in_sizes; (void)n_in; (void)out_size;

  Inputs in;
  for (int i = 0; i < 6; ++i) {
    in.cls[i] = (const float*)d_in[2 * i];
    in.reg[i] = (const float*)d_in[2 * i + 1];
  }

  char* ws = (char*)d_ws;
  size_t o = 0;
  float* dx1 = (float*)(ws + o); o += (size_t)NA * 4;
  float* dy1 = (float*)(ws + o); o += (size_t)NA * 4;
  float* dx2 = (float*)(ws + o); o += (size_t)NA * 4;
  float* dy2 = (float*)(ws + o); o += (size_t)NA * 4;
  float* dsc = (float*)(ws + o); o += (size_t)NA * 4;
  unsigned long long* ckey = (unsigned long long*)(ws + o); o += (size_t)NA * 8;
  float* sx1 = (float*)(ws + o); o += (size_t)NA * 4;
  float* sy1 = (float*)(ws + o); o += (size_t)NA * 4;
  float* sx2 = (float*)(ws + o); o += (size_t)NA * 4;
  float* sy2 = (float*)(ws + o); o += (size_t)NA * 4;
  unsigned int* sorig = (unsigned int*)(ws + o); o += (size_t)NA * 4;
  unsigned int* keepflag = (unsigned int*)(ws + o); o += (size_t)NA * 4;
  unsigned int* Mc = (unsigned int*)(ws + o); o += 64;
  o = (o + 511) & ~(size_t)511;
  unsigned long long* maskT = (unsigned long long*)(ws + o);
  size_t need = o + (size_t)W_MAX * NA * 8;   // ~57 MiB
  const bool fast = (need <= ws_size);        // ws_size constant -> graph-safe

  const int nb = (N_TOTAL + 255) / 256;  // 86

  if (fast) {
    (void)hipMemsetAsync((void*)Mc, 0, 64, stream);
    decode_kernel<<<nb, 256, 0, stream>>>(in, dx1, dy1, dx2, dy2, dsc, ckey, Mc,
                                          (float*)d_out);
    rank_kernel<<<nb, 1024, 0, stream>>>(ckey, Mc, dx1, dy1, dx2, dy2,
                                         sx1, sy1, sx2, sy2, sorig);
    pairs_kernel<<<dim3(86, W_MAX), 256, 0, stream>>>(sx1, sy1, sx2, sy2, Mc, maskT);
    scan_kernel<<<1, 1024, 0, stream>>>(maskT, sorig, Mc,
                                        dx1, dy1, dx2, dy2, dsc, (float*)d_out);
  } else {
    (void)hipMemsetAsync((void*)keepflag, 0, (size_t)NA * 4 + 64, stream);
    decode_kernel<<<nb, 256, 0, stream>>>(in, dx1, dy1, dx2, dy2, dsc, ckey, Mc,
                                          (float*)d_out);
    rank_kernel<<<nb, 1024, 0, stream>>>(ckey, Mc, dx1, dy1, dx2, dy2,
                                         sx1, sy1, sx2, sy2, sorig);
    nms_kernel<<<1, 1024, 0, stream>>>(sx1, sy1, sx2, sy2, sorig, Mc, keepflag);
    output_kernel<<<nb, 256, 0, stream>>>(dx1, dy1, dx2, dy2, dsc, keepflag,
                                          (float*)d_out);
  }
}

// Round 5
// 491.546 us; speedup vs baseline: 13.1232x; 1.0465x over previous
//
#include <hip/hip_runtime.h>
#include <stdint.h>

#define N_TOTAL 21840
#define NA      21888          // N_TOTAL rounded up to multiple of 64
#define W_MAX   342            // ceil(21840/64)
#define NMS_TH  0.3f
#define FINAL_TH 0.5f
#define NSLICE  8              // rank range-split factor
#define K_PRE   11             // prefetched cross-push words per wave (covers W<=177)

struct Inputs { const float* cls[6]; const float* reg[6]; };

// Raw barrier: drains LDS (lgkmcnt) but NOT vmem (vmcnt) — lets prefetched
// global loads stay in flight across the barrier. Only valid when barriers
// order LDS state only (true in scan_kernel: maskT is read-only).
__device__ __forceinline__ void block_bar() {
  asm volatile("s_waitcnt lgkmcnt(0)\n\ts_barrier" ::: "memory");
}

// ---------------------------------------------------------------- decode ----
__global__ void decode_kernel(Inputs in,
                              float* __restrict__ dx1, float* __restrict__ dy1,
                              float* __restrict__ dx2, float* __restrict__ dy2,
                              float* __restrict__ dsc,
                              unsigned long long* __restrict__ ckey,
                              unsigned int* __restrict__ Mc,
                              unsigned int* __restrict__ rank32,
                              float* __restrict__ out) {
#pragma clang fp contract(off)
  int gid = blockIdx.x * blockDim.x + threadIdx.x;
  if (gid >= N_TOTAL) return;

  rank32[gid] = 0u;                       // zeroed ahead of rank_kernel

  int sc, local;
  if      (gid < 16384) { sc = 0; local = gid;         }
  else if (gid < 20480) { sc = 1; local = gid - 16384; }
  else if (gid < 21504) { sc = 2; local = gid - 20480; }
  else if (gid < 21760) { sc = 3; local = gid - 21504; }
  else if (gid < 21824) { sc = 4; local = gid - 21760; }
  else                  { sc = 5; local = gid - 21824; }

  const int Wd     = 128 >> sc;
  const int stride = 4 << sc;
  const int HW     = Wd * Wd;
  const int x = local & (Wd - 1);
  const int y = local >> (7 - sc);

  const float* cls = in.cls[sc];
  const float* reg = in.reg[sc];

  float c0 = cls[local];
  float c1 = cls[HW + local];
  float m  = fmaxf(c0, c1);
  float e0 = expf(c0 - m);
  float e1 = expf(c1 - m);
  float prob = e1 / (e0 + e1);

  float l0 = reg[local];
  float l1 = reg[HW + local];
  float l2 = reg[2 * HW + local];
  float l3 = reg[3 * HW + local];

  float sF  = (float)stride;
  float pcx = 0.5f * sF + (float)x * sF;
  float pcy = 0.5f * sF + (float)y * sF;
  float pwh = sF * 4.0f;

  float cx = pcx + ((l0 * 0.1f) * pwh);
  float cy = pcy + ((l1 * 0.1f) * pwh);
  float w  = pwh * expf(l2 * 0.2f);
  float h  = pwh * expf(l3 * 0.2f);
  float x1 = cx - w * 0.5f;
  float y1 = cy - h * 0.5f;
  float x2 = x1 + w;
  float y2 = y1 + h;

  dx1[gid] = x1; dy1[gid] = y1; dx2[gid] = x2; dy2[gid] = y2; dsc[gid] = prob;

  // zero the output row; scan_kernel scatters kept rows afterwards
  out[gid * 5 + 0] = 0.0f;
  out[gid * 5 + 1] = 0.0f;
  out[gid * 5 + 2] = 0.0f;
  out[gid * 5 + 3] = 0.0f;
  out[gid * 5 + 4] = 0.0f;

  // Only boxes with score > FINAL_TH can affect the output (suppression only
  // flows downward in score order, and only >FINAL_TH rows are exposed).
  if (prob > FINAL_TH) {
    unsigned int pos = atomicAdd(Mc, 1u);
    ckey[pos] = ((unsigned long long)__float_as_uint(prob) << 32) |
                (unsigned int)(~(unsigned int)gid);
  }
}

// ---------------------------------------------------------------- rank ------
// Count-rank with 8-way key-range split: block (x,y) ranks candidates
// [x*256, x*256+256) against range slice y. Partial ranks joined via one
// packed atomicAdd (count in bits[24+], rank sum in low 24); 8th adder
// scatters the sorted SoA.
__global__ void __launch_bounds__(256)
rank_kernel(const unsigned long long* __restrict__ ckey,
            const unsigned int* __restrict__ Mc,
            const float* __restrict__ dx1, const float* __restrict__ dy1,
            const float* __restrict__ dx2, const float* __restrict__ dy2,
            float* __restrict__ sx1, float* __restrict__ sy1,
            float* __restrict__ sx2, float* __restrict__ sy2,
            unsigned int* __restrict__ sorig,
            unsigned int* __restrict__ rank32) {
  __shared__ unsigned long long tile[256];
  const unsigned int M = *Mc;
  if (blockIdx.x * 256u >= M) return;          // uniform per block
  const int t = (int)threadIdx.x;
  const int p = (int)blockIdx.x * 256 + t;
  unsigned long long mykey = (p < (int)M) ? ckey[p] : 0ull;
  const int S  = (int)((M + NSLICE - 1) / NSLICE);
  const int lo = (int)blockIdx.y * S;
  const int hi = min((int)M, lo + S);
  int partial = 0;
  const int nt = (hi > lo) ? ((hi - lo + 255) >> 8) : 0;
  for (int ti = 0; ti < nt; ++ti) {
    int j = lo + ti * 256 + t;
    tile[t] = (j < hi) ? ckey[j] : 0ull;       // 0 never > any real key
    __syncthreads();
#pragma unroll 8
    for (int q = 0; q < 256; ++q) partial += (tile[q] > mykey) ? 1 : 0;
    __syncthreads();
  }
  if (p < (int)M) {
    unsigned int pack = (unsigned int)partial | (1u << 24);
    unsigned int old  = atomicAdd(&rank32[p], pack);
    unsigned int newv = old + pack;
    if ((newv >> 24) == NSLICE) {              // I'm the last slice to land
      int r = (int)(newv & 0xFFFFFF);
      unsigned int orig = ~(unsigned int)(mykey & 0xffffffffull);
      sx1[r] = dx1[orig];
      sy1[r] = dy1[orig];
      sx2[r] = dx2[orig];
      sy2[r] = dy2[orig];
      sorig[r] = orig;
    }
  }
}

// ---------------------------------------------------------------- pairs -----
// maskT[cw * NA + row] bit c set iff box (cw*64+c) is suppressed by `row`.
__global__ void __launch_bounds__(256)
pairs_kernel(const float* __restrict__ sx1, const float* __restrict__ sy1,
             const float* __restrict__ sx2, const float* __restrict__ sy2,
             const unsigned int* __restrict__ Mc,
             unsigned long long* __restrict__ maskT) {
#pragma clang fp contract(off)
  const int M = (int)*Mc;
  const int W = (M + 63) >> 6;
  const int rw = (int)blockIdx.y;
  const int cw_base = (int)blockIdx.x << 2;
  if (rw >= W || cw_base >= W || cw_base + 3 < rw) return;

  const int t = (int)threadIdx.x;
  const int g = t >> 6, l = t & 63;
  const int cw = cw_base + g;

  __shared__ float cx1[256], cy1[256], cx2[256], cy2[256], car[256];
  {
    int c = (cw << 6) + l;
    if (cw < W && c < M) {
      float a = sx1[c], b = sy1[c], d = sx2[c], e = sy2[c];
      cx1[t] = a; cy1[t] = b; cx2[t] = d; cy2[t] = e;
      car[t] = (d - a + 1.0f) * (e - b + 1.0f);
    }
  }
  __syncthreads();
  if (cw >= W || cw < rw) return;

  const int r = (rw << 6) + l;
  unsigned long long bits = 0ull;
  if (r < M) {
    float ax1 = sx1[r], ay1 = sy1[r], ax2 = sx2[r], ay2 = sy2[r];
    float aarea = (ax2 - ax1 + 1.0f) * (ay2 - ay1 + 1.0f);
    const int cmax = min(64, M - (cw << 6));
    const int sb = g << 6;
    for (int cc = 0; cc < cmax; ++cc) {
      int cg = (cw << 6) + cc;
      if (cg > r) {
        float xx1 = fmaxf(ax1, cx1[sb + cc]);
        float yy1 = fmaxf(ay1, cy1[sb + cc]);
        float xx2 = fminf(ax2, cx2[sb + cc]);
        float yy2 = fminf(ay2, cy2[sb + cc]);
        float ww = fmaxf(xx2 - xx1 + 1.0f, 0.0f);
        float hh = fmaxf(yy2 - yy1 + 1.0f, 0.0f);
        float inter = ww * hh;
        float iou = inter / (aarea + car[sb + cc] - inter);
        if (iou > NMS_TH) bits |= (1ull << cc);
      }
    }
  }
  maskT[(size_t)cw * NA + r] = bits;
}

// ---------------------------------------------------------------- scan ------
// Single-block greedy scan. Raw barriers (no vmcnt drain) + one-step-ahead
// register prefetch of both the row block and the cross-push rows.
__global__ void __launch_bounds__(1024)
scan_kernel(const unsigned long long* __restrict__ maskT,
            const unsigned int* __restrict__ sorig,
            const unsigned int* __restrict__ Mc,
            const float* __restrict__ dx1, const float* __restrict__ dy1,
            const float* __restrict__ dx2, const float* __restrict__ dy2,
            const float* __restrict__ dsc,
            float* __restrict__ out) {
  __shared__ unsigned long long sup[W_MAX];
  __shared__ unsigned long long kmask[W_MAX];
  __shared__ unsigned long long keptmask_sh;
  const int t = (int)threadIdx.x;
  const int g = t >> 6, l = t & 63;
  const int M = (int)*Mc;
  const int W = (M + 63) >> 6;

  for (int i = t; i < W_MAX; i += 1024) sup[i] = 0ull;
  block_bar();

  // prologue prefetch for step 0
  unsigned long long v[K_PRE], u[K_PRE];
  unsigned long long rb = 0ull;
  if (g == 0) rb = (l < M) ? maskT[l] : 0ull;
#pragma unroll
  for (int k = 0; k < K_PRE; ++k) {
    int jw = 1 + g + (k << 4);
    v[k] = (jw < W) ? maskT[(size_t)jw * NA + l] : 0ull;
  }

  for (int w = 0; w < W; ++w) {
    const int base = w << 6;
    if (g == 0) {
      unsigned long long rowbits = rb;
      {   // prefetch next word's row block
        int nr = base + 64 + l;
        rb = (w + 1 < W && nr < M) ? maskT[(size_t)(w + 1) * NA + nr] : 0ull;
      }
      unsigned long long nz = __ballot(rowbits != 0ull);
      const int n = min(64, M - base);
      unsigned long long wordmask = (n >= 64) ? ~0ull : ((1ull << n) - 1ull);
      unsigned long long pend = (~sup[w]) & wordmask;
      unsigned long long kept = 0ull;
      unsigned long long act = pend & nz;
      while (act) {                       // iterations = #kept rows w/ bits
        int i = __builtin_ctzll(act);
        unsigned long long upto = (2ull << i) - 1ull;  // bits [0..i]
        kept |= pend & upto;
        unsigned long long ri = __shfl(rowbits, i);
        pend &= ~upto;
        pend &= ~ri;
        act = pend & nz;
      }
      kept |= pend;
      if (l == 0) { keptmask_sh = kept; kmask[w] = kept; }
    }
    // all waves: rotate prefetch buffers, issue next step's cross-push loads
#pragma unroll
    for (int k = 0; k < K_PRE; ++k) u[k] = v[k];
#pragma unroll
    for (int k = 0; k < K_PRE; ++k) {
      int jw2 = w + 2 + g + (k << 4);
      v[k] = (jw2 < W) ? maskT[(size_t)jw2 * NA + (base + 64) + l] : 0ull;
    }
    block_bar();                          // no vmcnt drain: loads stay in flight
    const unsigned long long km = keptmask_sh;
    if (km != 0ull && ((km >> l) & 1ull)) {
#pragma unroll
      for (int k = 0; k < K_PRE; ++k) {
        int jw = w + 1 + g + (k << 4);
        if (jw < W && u[k]) atomicOr(&sup[jw], u[k]);
      }
      for (int k = K_PRE; ; ++k) {        // tail: only reached when W > 177
        int jw = w + 1 + g + (k << 4);
        if (jw >= W) break;
        unsigned long long vv = maskT[(size_t)jw * NA + base + l];
        if (vv) atomicOr(&sup[jw], vv);
      }
    }
    block_bar();
  }

  // scatter kept rows into the (pre-zeroed) output
  for (int i = t; i < (W << 6); i += 1024) {
    if ((kmask[i >> 6] >> (i & 63)) & 1ull) {
      unsigned int orig = sorig[i];
      out[(size_t)orig * 5 + 0] = dx1[orig];
      out[(size_t)orig * 5 + 1] = dy1[orig];
      out[(size_t)orig * 5 + 2] = dx2[orig];
      out[(size_t)orig * 5 + 3] = dy2[orig];
      out[(size_t)orig * 5 + 4] = dsc[orig];
    }
  }
}

// ------------------------------------------------- fallback NMS (tiny ws) ---
__global__ void __launch_bounds__(1024)
nms_kernel(const float* __restrict__ sx1, const float* __restrict__ sy1,
           const float* __restrict__ sx2, const float* __restrict__ sy2,
           const unsigned int* __restrict__ sorig,
           const unsigned int* __restrict__ Mc,
           unsigned int* __restrict__ keepflag) {
#pragma clang fp contract(off)
  __shared__ unsigned long long sup[W_MAX];
  __shared__ unsigned long long inrow[64];
  __shared__ float wx1[64], wy1[64], wx2[64], wy2[64], warea[64];
  __shared__ unsigned long long keptmask_sh;

  const int t = (int)threadIdx.x;
  const int M = (int)*Mc;
  const int W = (M + 63) >> 6;

  for (int i = t; i < W_MAX; i += 1024) sup[i] = 0ull;
  __syncthreads();

  for (int w = 0; w < W; ++w) {
    const int base = w << 6;
    const int n = min(64, M - base);
    if (t < 64) {
      if (t < n) {
        float a = sx1[base + t], b = sy1[base + t];
        float c = sx2[base + t], d = sy2[base + t];
        wx1[t] = a; wy1[t] = b; wx2[t] = c; wy2[t] = d;
        warea[t] = (c - a + 1.0f) * (d - b + 1.0f);
      }
    } else if (t < 128) {
      inrow[t - 64] = 0ull;
    }
    __syncthreads();
    {
      int r = t & 63, seg = t >> 6;
      unsigned long long bits = 0ull;
      if (r < n) {
        float ax1 = wx1[r], ay1 = wy1[r], ax2 = wx2[r], ay2 = wy2[r];
        float aarea = warea[r];
        for (int c = seg * 4; c < seg * 4 + 4; ++c) {
          if (c > r && c < n) {
            float xx1 = fmaxf(ax1, wx1[c]);
            float yy1 = fmaxf(ay1, wy1[c]);
            float xx2 = fminf(ax2, wx2[c]);
            float yy2 = fminf(ay2, wy2[c]);
            float ww = fmaxf(xx2 - xx1 + 1.0f, 0.0f);
            float hh = fmaxf(yy2 - yy1 + 1.0f, 0.0f);
            float inter = ww * hh;
            float iou = inter / (aarea + warea[c] - inter);
            if (iou > NMS_TH) bits |= (1ull << c);
          }
        }
      }
      if (bits) atomicOr(&inrow[r], bits);
    }
    __syncthreads();
    if (t < 64) {
      unsigned long long wordmask = (n >= 64) ? ~0ull : ((1ull << n) - 1ull);
      unsigned long long pending = (~sup[w]) & wordmask;
      unsigned long long kept = 0ull;
      while (pending) {
        int i = __builtin_ctzll(pending);
        kept |= (1ull << i);
        pending &= ~(inrow[i] | (1ull << i));
      }
      if (t == 0) keptmask_sh = kept;
      if (t < n && ((kept >> t) & 1ull)) keepflag[sorig[base + t]] = 1u;
    }
    __syncthreads();
    unsigned long long km = keptmask_sh;
    if (km) {
      int wid = t >> 6, lane = t & 63;
      for (int jw = w + 1 + wid; (jw << 6) < M; jw += 16) {
        int j = (jw << 6) + lane;
        bool supj = false;
        if (j < M) {
          float jx1 = sx1[j], jy1 = sy1[j], jx2 = sx2[j], jy2 = sy2[j];
          float jarea = (jx2 - jx1 + 1.0f) * (jy2 - jy1 + 1.0f);
          unsigned long long mm = km;
          while (mm) {
            int r = __builtin_ctzll(mm);
            mm &= mm - 1ull;
            float xx1 = fmaxf(wx1[r], jx1);
            float yy1 = fmaxf(wy1[r], jy1);
            float xx2 = fminf(wx2[r], jx2);
            float yy2 = fminf(wy2[r], jy2);
            float ww = fmaxf(xx2 - xx1 + 1.0f, 0.0f);
            float hh = fmaxf(yy2 - yy1 + 1.0f, 0.0f);
            float inter = ww * hh;
            float iou = inter / (warea[r] + jarea - inter);
            if (iou > NMS_TH) { supj = true; break; }
          }
        }
        unsigned long long bal = __ballot(supj);
        if (lane == 0 && bal) atomicOr(&sup[jw], bal);
      }
    }
    __syncthreads();
  }
}

// ---------------------------------------------------------------- output ----
// (fallback path only)
__global__ void output_kernel(const float* __restrict__ dx1, const float* __restrict__ dy1,
                              const float* __restrict__ dx2, const float* __restrict__ dy2,
                              const float* __restrict__ dsc,
                              const unsigned int* __restrict__ keepflag,
                              float* __restrict__ out) {
#pragma clang fp contract(off)
  int gid = blockIdx.x * blockDim.x + threadIdx.x;
  if (gid >= N_TOTAL) return;
  float f = keepflag[gid] ? 1.0f : 0.0f;
  out[gid * 5 + 0] = dx1[gid] * f;
  out[gid * 5 + 1] = dy1[gid] * f;
  out[gid * 5 + 2] = dx2[gid] * f;
  out[gid * 5 + 3] = dy2[gid] * f;
  out[gid * 5 + 4] = dsc[gid] * f;
}

// ---------------------------------------------------------------- launch ----
extern "C" void kernel_launch(void* const* d_in, const int* in_sizes, int n_in,
                              void* d_out, int out_size, void* d_ws, size_t ws_size,
                              hipStream_t stream) {
  (void)in_sizes; (void)n_in; (void)out_size;

  Inputs in;
  for (int i = 0; i < 6; ++i) {
    in.cls[i] = (const float*)d_in[2 * i];
    in.reg[i] = (const float*)d_in[2 * i + 1];
  }

  char* ws = (char*)d_ws;
  size_t o = 0;
  float* dx1 = (float*)(ws + o); o += (size_t)NA * 4;
  float* dy1 = (float*)(ws + o); o += (size_t)NA * 4;
  float* dx2 = (float*)(ws + o); o += (size_t)NA * 4;
  float* dy2 = (float*)(ws + o); o += (size_t)NA * 4;
  float* dsc = (float*)(ws + o); o += (size_t)NA * 4;
  unsigned long long* ckey = (unsigned long long*)(ws + o); o += (size_t)NA * 8;
  float* sx1 = (float*)(ws + o); o += (size_t)NA * 4;
  float* sy1 = (float*)(ws + o); o += (size_t)NA * 4;
  float* sx2 = (float*)(ws + o); o += (size_t)NA * 4;
  float* sy2 = (float*)(ws + o); o += (size_t)NA * 4;
  unsigned int* sorig = (unsigned int*)(ws + o); o += (size_t)NA * 4;
  unsigned int* keepflag = (unsigned int*)(ws + o); o += (size_t)NA * 4;
  unsigned int* rank32 = (unsigned int*)(ws + o); o += (size_t)NA * 4;
  unsigned int* Mc = (unsigned int*)(ws + o); o += 64;
  o = (o + 511) & ~(size_t)511;
  unsigned long long* maskT = (unsigned long long*)(ws + o);
  size_t need = o + (size_t)W_MAX * NA * 8;   // ~57 MiB
  const bool fast = (need <= ws_size);        // ws_size constant -> graph-safe

  const int nb = (N_TOTAL + 255) / 256;  // 86

  if (fast) {
    (void)hipMemsetAsync((void*)Mc, 0, 64, stream);
    decode_kernel<<<nb, 256, 0, stream>>>(in, dx1, dy1, dx2, dy2, dsc, ckey, Mc,
                                          rank32, (float*)d_out);
    rank_kernel<<<dim3(nb, NSLICE), 256, 0, stream>>>(ckey, Mc, dx1, dy1, dx2, dy2,
                                                      sx1, sy1, sx2, sy2, sorig,
                                                      rank32);
    pairs_kernel<<<dim3(86, W_MAX), 256, 0, stream>>>(sx1, sy1, sx2, sy2, Mc, maskT);
    scan_kernel<<<1, 1024, 0, stream>>>(maskT, sorig, Mc,
                                        dx1, dy1, dx2, dy2, dsc, (float*)d_out);
  } else {
    // fallback: zero keepflag + rank32 + Mc (contiguous)
    (void)hipMemsetAsync((void*)keepflag, 0, (size_t)NA * 8 + 64, stream);
    decode_kernel<<<nb, 256, 0, stream>>>(in, dx1, dy1, dx2, dy2, dsc, ckey, Mc,
                                          rank32, (float*)d_out);
    rank_kernel<<<dim3(nb, NSLICE), 256, 0, stream>>>(ckey, Mc, dx1, dy1, dx2, dy2,
                                                      sx1, sy1, sx2, sy2, sorig,
                                                      rank32);
    nms_kernel<<<1, 1024, 0, stream>>>(sx1, sy1, sx2, sy2, sorig, Mc, keepflag);
    output_kernel<<<nb, 256, 0, stream>>>(dx1, dy1, dx2, dy2, dsc, keepflag,
                                          (float*)d_out);
  }
}

// Round 6
// 418.097 us; speedup vs baseline: 15.4287x; 1.1757x over previous
//
#include <hip/hip_runtime.h>
#include <stdint.h>

#define N_TOTAL 21840
#define NA      21888          // N_TOTAL rounded up to multiple of 64
#define W_MAX   342            // ceil(21840/64)
#define NMS_TH  0.3f
#define FINAL_TH 0.5f
#define NSLICE  8              // rank range-split factor

struct Inputs { const float* cls[6]; const float* reg[6]; };

// Raw barrier: drains LDS (lgkmcnt) but NOT vmem (vmcnt) — lets prefetched
// global loads stay in flight across the barrier. Only valid when barriers
// order LDS state only (true in scan_kernel: maskT is read-only).
__device__ __forceinline__ void block_bar() {
  asm volatile("s_waitcnt lgkmcnt(0)\n\ts_barrier" ::: "memory");
}

// ---------------------------------------------------------------- decode ----
__global__ void decode_kernel(Inputs in,
                              float* __restrict__ dx1, float* __restrict__ dy1,
                              float* __restrict__ dx2, float* __restrict__ dy2,
                              float* __restrict__ dsc,
                              unsigned long long* __restrict__ ckey,
                              unsigned int* __restrict__ Mc,
                              unsigned int* __restrict__ rank32,
                              float* __restrict__ out) {
#pragma clang fp contract(off)
  int gid = blockIdx.x * blockDim.x + threadIdx.x;
  if (gid >= N_TOTAL) return;

  rank32[gid] = 0u;                       // zeroed ahead of rank_kernel

  int sc, local;
  if      (gid < 16384) { sc = 0; local = gid;         }
  else if (gid < 20480) { sc = 1; local = gid - 16384; }
  else if (gid < 21504) { sc = 2; local = gid - 20480; }
  else if (gid < 21760) { sc = 3; local = gid - 21504; }
  else if (gid < 21824) { sc = 4; local = gid - 21760; }
  else                  { sc = 5; local = gid - 21824; }

  const int Wd     = 128 >> sc;
  const int stride = 4 << sc;
  const int HW     = Wd * Wd;
  const int x = local & (Wd - 1);
  const int y = local >> (7 - sc);

  const float* cls = in.cls[sc];
  const float* reg = in.reg[sc];

  float c0 = cls[local];
  float c1 = cls[HW + local];
  float m  = fmaxf(c0, c1);
  float e0 = expf(c0 - m);
  float e1 = expf(c1 - m);
  float prob = e1 / (e0 + e1);

  float l0 = reg[local];
  float l1 = reg[HW + local];
  float l2 = reg[2 * HW + local];
  float l3 = reg[3 * HW + local];

  float sF  = (float)stride;
  float pcx = 0.5f * sF + (float)x * sF;
  float pcy = 0.5f * sF + (float)y * sF;
  float pwh = sF * 4.0f;

  float cx = pcx + ((l0 * 0.1f) * pwh);
  float cy = pcy + ((l1 * 0.1f) * pwh);
  float w  = pwh * expf(l2 * 0.2f);
  float h  = pwh * expf(l3 * 0.2f);
  float x1 = cx - w * 0.5f;
  float y1 = cy - h * 0.5f;
  float x2 = x1 + w;
  float y2 = y1 + h;

  dx1[gid] = x1; dy1[gid] = y1; dx2[gid] = x2; dy2[gid] = y2; dsc[gid] = prob;

  // zero the output row; scan_kernel scatters kept rows afterwards
  out[gid * 5 + 0] = 0.0f;
  out[gid * 5 + 1] = 0.0f;
  out[gid * 5 + 2] = 0.0f;
  out[gid * 5 + 3] = 0.0f;
  out[gid * 5 + 4] = 0.0f;

  // Only boxes with score > FINAL_TH can affect the output (suppression only
  // flows downward in score order, and only >FINAL_TH rows are exposed).
  if (prob > FINAL_TH) {
    unsigned int pos = atomicAdd(Mc, 1u);
    ckey[pos] = ((unsigned long long)__float_as_uint(prob) << 32) |
                (unsigned int)(~(unsigned int)gid);
  }
}

// ---------------------------------------------------------------- rank ------
// Count-rank with 8-way key-range split; packed atomicAdd join.
__global__ void __launch_bounds__(256)
rank_kernel(const unsigned long long* __restrict__ ckey,
            const unsigned int* __restrict__ Mc,
            const float* __restrict__ dx1, const float* __restrict__ dy1,
            const float* __restrict__ dx2, const float* __restrict__ dy2,
            float* __restrict__ sx1, float* __restrict__ sy1,
            float* __restrict__ sx2, float* __restrict__ sy2,
            unsigned int* __restrict__ sorig,
            unsigned int* __restrict__ rank32) {
  __shared__ unsigned long long tile[256];
  const unsigned int M = *Mc;
  if (blockIdx.x * 256u >= M) return;          // uniform per block
  const int t = (int)threadIdx.x;
  const int p = (int)blockIdx.x * 256 + t;
  unsigned long long mykey = (p < (int)M) ? ckey[p] : 0ull;
  const int S  = (int)((M + NSLICE - 1) / NSLICE);
  const int lo = (int)blockIdx.y * S;
  const int hi = min((int)M, lo + S);
  int partial = 0;
  const int nt = (hi > lo) ? ((hi - lo + 255) >> 8) : 0;
  for (int ti = 0; ti < nt; ++ti) {
    int j = lo + ti * 256 + t;
    tile[t] = (j < hi) ? ckey[j] : 0ull;       // 0 never > any real key
    __syncthreads();
#pragma unroll 8
    for (int q = 0; q < 256; ++q) partial += (tile[q] > mykey) ? 1 : 0;
    __syncthreads();
  }
  if (p < (int)M) {
    unsigned int pack = (unsigned int)partial | (1u << 24);
    unsigned int old  = atomicAdd(&rank32[p], pack);
    unsigned int newv = old + pack;
    if ((newv >> 24) == NSLICE) {              // last slice to land scatters
      int r = (int)(newv & 0xFFFFFF);
      unsigned int orig = ~(unsigned int)(mykey & 0xffffffffull);
      sx1[r] = dx1[orig];
      sy1[r] = dy1[orig];
      sx2[r] = dx2[orig];
      sy2[r] = dy2[orig];
      sorig[r] = orig;
    }
  }
}

// ---------------------------------------------------------------- pairs -----
// maskT[cw * NA + row] bit c set iff box (cw*64+c) is suppressed by `row`.
__global__ void __launch_bounds__(256)
pairs_kernel(const float* __restrict__ sx1, const float* __restrict__ sy1,
             const float* __restrict__ sx2, const float* __restrict__ sy2,
             const unsigned int* __restrict__ Mc,
             unsigned long long* __restrict__ maskT) {
#pragma clang fp contract(off)
  const int M = (int)*Mc;
  const int W = (M + 63) >> 6;
  const int rw = (int)blockIdx.y;
  const int cw_base = (int)blockIdx.x << 2;
  if (rw >= W || cw_base >= W || cw_base + 3 < rw) return;

  const int t = (int)threadIdx.x;
  const int g = t >> 6, l = t & 63;
  const int cw = cw_base + g;

  __shared__ float cx1[256], cy1[256], cx2[256], cy2[256], car[256];
  {
    int c = (cw << 6) + l;
    if (cw < W && c < M) {
      float a = sx1[c], b = sy1[c], d = sx2[c], e = sy2[c];
      cx1[t] = a; cy1[t] = b; cx2[t] = d; cy2[t] = e;
      car[t] = (d - a + 1.0f) * (e - b + 1.0f);
    }
  }
  __syncthreads();
  if (cw >= W || cw < rw) return;

  const int r = (rw << 6) + l;
  unsigned long long bits = 0ull;
  if (r < M) {
    float ax1 = sx1[r], ay1 = sy1[r], ax2 = sx2[r], ay2 = sy2[r];
    float aarea = (ax2 - ax1 + 1.0f) * (ay2 - ay1 + 1.0f);
    const int cmax = min(64, M - (cw << 6));
    const int sb = g << 6;
    for (int cc = 0; cc < cmax; ++cc) {
      int cg = (cw << 6) + cc;
      if (cg > r) {
        float xx1 = fmaxf(ax1, cx1[sb + cc]);
        float yy1 = fmaxf(ay1, cy1[sb + cc]);
        float xx2 = fminf(ax2, cx2[sb + cc]);
        float yy2 = fminf(ay2, cy2[sb + cc]);
        float ww = fmaxf(xx2 - xx1 + 1.0f, 0.0f);
        float hh = fmaxf(yy2 - yy1 + 1.0f, 0.0f);
        float inter = ww * hh;
        float iou = inter / (aarea + car[sb + cc] - inter);
        if (iou > NMS_TH) bits |= (1ull << cc);
      }
    }
  }
  maskT[(size_t)cw * NA + r] = bits;
}

// ---------------------------------------------------------------- scan ------
// Single-block greedy scan, producer-consumer: wave 0 scans word-by-word and
// carries the w->w+1 push in registers (shfl-OR); waves 1-15 apply pushes
// into sup[jw>=w+2] with named-scalar deep prefetch. ONE barrier per step.
// Race-freedom: step-w pushes target >= w+2 and are fenced by barrier #(w+1)
// before the scanner reads them; kmls[w] is write-once.
__global__ void __launch_bounds__(1024)
scan_kernel(const unsigned long long* __restrict__ maskT,
            const unsigned int* __restrict__ sorig,
            const unsigned int* __restrict__ Mc,
            const float* __restrict__ dx1, const float* __restrict__ dy1,
            const float* __restrict__ dx2, const float* __restrict__ dy2,
            const float* __restrict__ dsc,
            float* __restrict__ out) {
  __shared__ unsigned long long sup[W_MAX];
  __shared__ unsigned long long kmls[W_MAX];
  const int t = (int)threadIdx.x;
  const int g = t >> 6, l = t & 63;
  const int M = (int)*Mc;
  const int W = (M + 63) >> 6;

  for (int i = t; i < W_MAX; i += 1024) { sup[i] = 0ull; kmls[i] = 0ull; }
  block_bar();

  if (g == 0) {
    // -------- scanner wave --------
    unsigned long long rb   = (l < M) ? maskT[l] : 0ull;              // word0 in-word rows
    unsigned long long pv   = (W > 1) ? maskT[(size_t)NA + l] : 0ull; // rows word0, col word1
    unsigned long long inln = 0ull;                                   // carried w-1 -> w push
    for (int w = 0; w < W; ++w) {
      const int base = w << 6;
      unsigned long long supw = sup[w];
      unsigned long long rowbits = rb;
      unsigned long long pvc = pv;
      {   // prefetch next step's two blocks (named scalars)
        int rn = base + 64 + l;
        rb = (w + 1 < W && rn < M) ? maskT[(size_t)(w + 1) * NA + rn] : 0ull;
        pv = (w + 2 < W) ? maskT[(size_t)(w + 2) * NA + base + 64 + l] : 0ull;
      }
      unsigned long long nz = __ballot(rowbits != 0ull);
      const int n = min(64, M - base);
      unsigned long long wordmask = (n >= 64) ? ~0ull : ((1ull << n) - 1ull);
      unsigned long long pend = (~(supw | inln)) & wordmask;
      unsigned long long kept = 0ull;
      unsigned long long act = pend & nz;
      while (act) {                       // iterations = #kept rows w/ bits
        int i = __builtin_ctzll(act);
        unsigned long long upto = (2ull << i) - 1ull;  // bits [0..i]
        kept |= pend & upto;
        unsigned long long ri = __shfl(rowbits, i);
        pend &= ~upto;
        pend &= ~ri;
        act = pend & nz;
      }
      kept |= pend;
      if (l == 0) kmls[w] = kept;
      // inline push w -> w+1: OR of pvc over kept lanes (in-register)
      unsigned long long x = ((kept >> l) & 1ull) ? pvc : 0ull;
#pragma unroll
      for (int off = 32; off; off >>= 1) x |= __shfl_xor(x, off);
      inln = x;
      block_bar();
    }
  } else {
    // -------- pusher waves (stride 15, 12 prefetched words each) --------
    const int gs = g - 1;
    unsigned long long v0, v1, v2, v3, v4, v5, v6, v7, v8, v9, v10, v11;
#define SCAN_ISSUE(K, VK) { int jw = 2 + gs + 15 * K; \
    VK = (jw < W) ? maskT[(size_t)jw * NA + l] : 0ull; }
    SCAN_ISSUE(0, v0)  SCAN_ISSUE(1, v1)  SCAN_ISSUE(2, v2)  SCAN_ISSUE(3, v3)
    SCAN_ISSUE(4, v4)  SCAN_ISSUE(5, v5)  SCAN_ISSUE(6, v6)  SCAN_ISSUE(7, v7)
    SCAN_ISSUE(8, v8)  SCAN_ISSUE(9, v9)  SCAN_ISSUE(10, v10) SCAN_ISSUE(11, v11)
#undef SCAN_ISSUE
    for (int w = 0; w < W; ++w) {
      block_bar();
      const unsigned long long km = kmls[w];
      const bool mine = ((km >> l) & 1ull) != 0ull;
      const int base = w << 6;
#define SCAN_APPLY(K, VK) { int jw = w + 2 + gs + 15 * K; \
    if (jw < W && mine && VK) atomicOr(&sup[jw], VK); }
      SCAN_APPLY(0, v0)  SCAN_APPLY(1, v1)  SCAN_APPLY(2, v2)  SCAN_APPLY(3, v3)
      SCAN_APPLY(4, v4)  SCAN_APPLY(5, v5)  SCAN_APPLY(6, v6)  SCAN_APPLY(7, v7)
      SCAN_APPLY(8, v8)  SCAN_APPLY(9, v9)  SCAN_APPLY(10, v10) SCAN_APPLY(11, v11)
#undef SCAN_APPLY
      for (int jw = w + 2 + gs + 180; jw < W; jw += 15) {   // only when W > 182
        unsigned long long vv = maskT[(size_t)jw * NA + base + l];
        if (mine && vv) atomicOr(&sup[jw], vv);
      }
      const int rown = base + 64 + l;
#define SCAN_REISSUE(K, VK) { int jw = w + 3 + gs + 15 * K; \
    VK = (jw < W) ? maskT[(size_t)jw * NA + rown] : 0ull; }
      SCAN_REISSUE(0, v0)  SCAN_REISSUE(1, v1)  SCAN_REISSUE(2, v2)  SCAN_REISSUE(3, v3)
      SCAN_REISSUE(4, v4)  SCAN_REISSUE(5, v5)  SCAN_REISSUE(6, v6)  SCAN_REISSUE(7, v7)
      SCAN_REISSUE(8, v8)  SCAN_REISSUE(9, v9)  SCAN_REISSUE(10, v10) SCAN_REISSUE(11, v11)
#undef SCAN_REISSUE
    }
  }
  block_bar();

  // scatter kept rows into the (pre-zeroed) output
  for (int i = t; i < (W << 6); i += 1024) {
    if ((kmls[i >> 6] >> (i & 63)) & 1ull) {
      unsigned int orig = sorig[i];
      out[(size_t)orig * 5 + 0] = dx1[orig];
      out[(size_t)orig * 5 + 1] = dy1[orig];
      out[(size_t)orig * 5 + 2] = dx2[orig];
      out[(size_t)orig * 5 + 3] = dy2[orig];
      out[(size_t)orig * 5 + 4] = dsc[orig];
    }
  }
}

// ------------------------------------------------- fallback NMS (tiny ws) ---
__global__ void __launch_bounds__(1024)
nms_kernel(const float* __restrict__ sx1, const float* __restrict__ sy1,
           const float* __restrict__ sx2, const float* __restrict__ sy2,
           const unsigned int* __restrict__ sorig,
           const unsigned int* __restrict__ Mc,
           unsigned int* __restrict__ keepflag) {
#pragma clang fp contract(off)
  __shared__ unsigned long long sup[W_MAX];
  __shared__ unsigned long long inrow[64];
  __shared__ float wx1[64], wy1[64], wx2[64], wy2[64], warea[64];
  __shared__ unsigned long long keptmask_sh;

  const int t = (int)threadIdx.x;
  const int M = (int)*Mc;
  const int W = (M + 63) >> 6;

  for (int i = t; i < W_MAX; i += 1024) sup[i] = 0ull;
  __syncthreads();

  for (int w = 0; w < W; ++w) {
    const int base = w << 6;
    const int n = min(64, M - base);
    if (t < 64) {
      if (t < n) {
        float a = sx1[base + t], b = sy1[base + t];
        float c = sx2[base + t], d = sy2[base + t];
        wx1[t] = a; wy1[t] = b; wx2[t] = c; wy2[t] = d;
        warea[t] = (c - a + 1.0f) * (d - b + 1.0f);
      }
    } else if (t < 128) {
      inrow[t - 64] = 0ull;
    }
    __syncthreads();
    {
      int r = t & 63, seg = t >> 6;
      unsigned long long bits = 0ull;
      if (r < n) {
        float ax1 = wx1[r], ay1 = wy1[r], ax2 = wx2[r], ay2 = wy2[r];
        float aarea = warea[r];
        for (int c = seg * 4; c < seg * 4 + 4; ++c) {
          if (c > r && c < n) {
            float xx1 = fmaxf(ax1, wx1[c]);
            float yy1 = fmaxf(ay1, wy1[c]);
            float xx2 = fminf(ax2, wx2[c]);
            float yy2 = fminf(ay2, wy2[c]);
            float ww = fmaxf(xx2 - xx1 + 1.0f, 0.0f);
            float hh = fmaxf(yy2 - yy1 + 1.0f, 0.0f);
            float inter = ww * hh;
            float iou = inter / (aarea + warea[c] - inter);
            if (iou > NMS_TH) bits |= (1ull << c);
          }
        }
      }
      if (bits) atomicOr(&inrow[r], bits);
    }
    __syncthreads();
    if (t < 64) {
      unsigned long long wordmask = (n >= 64) ? ~0ull : ((1ull << n) - 1ull);
      unsigned long long pending = (~sup[w]) & wordmask;
      unsigned long long kept = 0ull;
      while (pending) {
        int i = __builtin_ctzll(pending);
        kept |= (1ull << i);
        pending &= ~(inrow[i] | (1ull << i));
      }
      if (t == 0) keptmask_sh = kept;
      if (t < n && ((kept >> t) & 1ull)) keepflag[sorig[base + t]] = 1u;
    }
    __syncthreads();
    unsigned long long km = keptmask_sh;
    if (km) {
      int wid = t >> 6, lane = t & 63;
      for (int jw = w + 1 + wid; (jw << 6) < M; jw += 16) {
        int j = (jw << 6) + lane;
        bool supj = false;
        if (j < M) {
          float jx1 = sx1[j], jy1 = sy1[j], jx2 = sx2[j], jy2 = sy2[j];
          float jarea = (jx2 - jx1 + 1.0f) * (jy2 - jy1 + 1.0f);
          unsigned long long mm = km;
          while (mm) {
            int r = __builtin_ctzll(mm);
            mm &= mm - 1ull;
            float xx1 = fmaxf(wx1[r], jx1);
            float yy1 = fmaxf(wy1[r], jy1);
            float xx2 = fminf(wx2[r], jx2);
            float yy2 = fminf(wy2[r], jy2);
            float ww = fmaxf(xx2 - xx1 + 1.0f, 0.0f);
            float hh = fmaxf(yy2 - yy1 + 1.0f, 0.0f);
            float inter = ww * hh;
            float iou = inter / (warea[r] + jarea - inter);
            if (iou > NMS_TH) { supj = true; break; }
          }
        }
        unsigned long long bal = __ballot(supj);
        if (lane == 0 && bal) atomicOr(&sup[jw], bal);
      }
    }
    __syncthreads();
  }
}

// ---------------------------------------------------------------- output ----
// (fallback path only)
__global__ void output_kernel(const float* __restrict__ dx1, const float* __restrict__ dy1,
                              const float* __restrict__ dx2, const float* __restrict__ dy2,
                              const float* __restrict__ dsc,
                              const unsigned int* __restrict__ keepflag,
                              float* __restrict__ out) {
#pragma clang fp contract(off)
  int gid = blockIdx.x * blockDim.x + threadIdx.x;
  if (gid >= N_TOTAL) return;
  float f = keepflag[gid] ? 1.0f : 0.0f;
  out[gid * 5 + 0] = dx1[gid] * f;
  out[gid * 5 + 1] = dy1[gid] * f;
  out[gid * 5 + 2] = dx2[gid] * f;
  out[gid * 5 + 3] = dy2[gid] * f;
  out[gid * 5 + 4] = dsc[gid] * f;
}

// ---------------------------------------------------------------- launch ----
extern "C" void kernel_launch(void* const* d_in, const int* in_sizes, int n_in,
                              void* d_out, int out_size, void* d_ws, size_t ws_size,
                              hipStream_t stream) {
  (void)in_sizes; (void)n_in; (void)out_size;

  Inputs in;
  for (int i = 0; i < 6; ++i) {
    in.cls[i] = (const float*)d_in[2 * i];
    in.reg[i] = (const float*)d_in[2 * i + 1];
  }

  char* ws = (char*)d_ws;
  size_t o = 0;
  float* dx1 = (float*)(ws + o); o += (size_t)NA * 4;
  float* dy1 = (float*)(ws + o); o += (size_t)NA * 4;
  float* dx2 = (float*)(ws + o); o += (size_t)NA * 4;
  float* dy2 = (float*)(ws + o); o += (size_t)NA * 4;
  float* dsc = (float*)(ws + o); o += (size_t)NA * 4;
  unsigned long long* ckey = (unsigned long long*)(ws + o); o += (size_t)NA * 8;
  float* sx1 = (float*)(ws + o); o += (size_t)NA * 4;
  float* sy1 = (float*)(ws + o); o += (size_t)NA * 4;
  float* sx2 = (float*)(ws + o); o += (size_t)NA * 4;
  float* sy2 = (float*)(ws + o); o += (size_t)NA * 4;
  unsigned int* sorig = (unsigned int*)(ws + o); o += (size_t)NA * 4;
  unsigned int* keepflag = (unsigned int*)(ws + o); o += (size_t)NA * 4;
  unsigned int* rank32 = (unsigned int*)(ws + o); o += (size_t)NA * 4;
  unsigned int* Mc = (unsigned int*)(ws + o); o += 64;
  o = (o + 511) & ~(size_t)511;
  unsigned long long* maskT = (unsigned long long*)(ws + o);
  size_t need = o + (size_t)W_MAX * NA * 8;   // ~57 MiB
  const bool fast = (need <= ws_size);        // ws_size constant -> graph-safe

  const int nb = (N_TOTAL + 255) / 256;  // 86

  if (fast) {
    (void)hipMemsetAsync((void*)Mc, 0, 64, stream);
    decode_kernel<<<nb, 256, 0, stream>>>(in, dx1, dy1, dx2, dy2, dsc, ckey, Mc,
                                          rank32, (float*)d_out);
    rank_kernel<<<dim3(nb, NSLICE), 256, 0, stream>>>(ckey, Mc, dx1, dy1, dx2, dy2,
                                                      sx1, sy1, sx2, sy2, sorig,
                                                      rank32);
    pairs_kernel<<<dim3(86, W_MAX), 256, 0, stream>>>(sx1, sy1, sx2, sy2, Mc, maskT);
    scan_kernel<<<1, 1024, 0, stream>>>(maskT, sorig, Mc,
                                        dx1, dy1, dx2, dy2, dsc, (float*)d_out);
  } else {
    // fallback: zero keepflag + rank32 + Mc (contiguous)
    (void)hipMemsetAsync((void*)keepflag, 0, (size_t)NA * 8 + 64, stream);
    decode_kernel<<<nb, 256, 0, stream>>>(in, dx1, dy1, dx2, dy2, dsc, ckey, Mc,
                                          rank32, (float*)d_out);
    rank_kernel<<<dim3(nb, NSLICE), 256, 0, stream>>>(ckey, Mc, dx1, dy1, dx2, dy2,
                                                      sx1, sy1, sx2, sy2, sorig,
                                                      rank32);
    nms_kernel<<<1, 1024, 0, stream>>>(sx1, sy1, sx2, sy2, sorig, Mc, keepflag);
    output_kernel<<<nb, 256, 0, stream>>>(dx1, dy1, dx2, dy2, dsc, keepflag,
                                          (float*)d_out);
  }
}

// Round 7
// 346.489 us; speedup vs baseline: 18.6173x; 1.2067x over previous
//
#include <hip/hip_runtime.h>
#include <stdint.h>

#define N_TOTAL 21840
#define NA      21888          // N_TOTAL rounded up to multiple of 64
#define W_MAX   342            // ceil(21840/64)
#define TOT_ENT 3753792u       // 64 * (342*343/2)  triangular CSR capacity
#define NMS_TH  0.3f
#define FINAL_TH 0.5f
#define NSLICE  8              // rank range-split factor

struct Inputs { const float* cls[6]; const float* reg[6]; };

// Raw barrier: drains LDS (lgkmcnt) but NOT vmem (vmcnt) — lets prefetched
// global loads stay in flight across the barrier. Only valid when barriers
// order LDS state only (true in scan_kernel: all global inputs read-only).
__device__ __forceinline__ void block_bar() {
  asm volatile("s_waitcnt lgkmcnt(0)\n\ts_barrier" ::: "memory");
}

// Closed-form CSR row base: row r (sorted pos) owns 342-(r>>6) slots.
__device__ __forceinline__ unsigned rowbase_u(unsigned r) {
  unsigned w = r >> 6, l = r & 63u;
  return 64u * (342u * w - (w * (w - 1u)) / 2u) + l * (342u - w);
}

// ---------------------------------------------------------------- decode ----
__global__ void decode_kernel(Inputs in,
                              float* __restrict__ dx1, float* __restrict__ dy1,
                              float* __restrict__ dx2, float* __restrict__ dy2,
                              float* __restrict__ dsc,
                              unsigned long long* __restrict__ ckey,
                              unsigned int* __restrict__ Mc,
                              unsigned int* __restrict__ rank32,
                              unsigned int* __restrict__ cnt,
                              float* __restrict__ out) {
#pragma clang fp contract(off)
  int gid = blockIdx.x * blockDim.x + threadIdx.x;
  if (gid >= N_TOTAL) return;

  rank32[gid] = 0u;                       // zeroed ahead of rank_kernel
  cnt[gid] = 0u;                          // CSR row counts
  if (gid < NA - N_TOTAL) cnt[N_TOTAL + gid] = 0u;   // tail rows

  int sc, local;
  if      (gid < 16384) { sc = 0; local = gid;         }
  else if (gid < 20480) { sc = 1; local = gid - 16384; }
  else if (gid < 21504) { sc = 2; local = gid - 20480; }
  else if (gid < 21760) { sc = 3; local = gid - 21504; }
  else if (gid < 21824) { sc = 4; local = gid - 21760; }
  else                  { sc = 5; local = gid - 21824; }

  const int Wd     = 128 >> sc;
  const int stride = 4 << sc;
  const int HW     = Wd * Wd;
  const int x = local & (Wd - 1);
  const int y = local >> (7 - sc);

  const float* cls = in.cls[sc];
  const float* reg = in.reg[sc];

  float c0 = cls[local];
  float c1 = cls[HW + local];
  float m  = fmaxf(c0, c1);
  float e0 = expf(c0 - m);
  float e1 = expf(c1 - m);
  float prob = e1 / (e0 + e1);

  float l0 = reg[local];
  float l1 = reg[HW + local];
  float l2 = reg[2 * HW + local];
  float l3 = reg[3 * HW + local];

  float sF  = (float)stride;
  float pcx = 0.5f * sF + (float)x * sF;
  float pcy = 0.5f * sF + (float)y * sF;
  float pwh = sF * 4.0f;

  float cx = pcx + ((l0 * 0.1f) * pwh);
  float cy = pcy + ((l1 * 0.1f) * pwh);
  float w  = pwh * expf(l2 * 0.2f);
  float h  = pwh * expf(l3 * 0.2f);
  float x1 = cx - w * 0.5f;
  float y1 = cy - h * 0.5f;
  float x2 = x1 + w;
  float y2 = y1 + h;

  dx1[gid] = x1; dy1[gid] = y1; dx2[gid] = x2; dy2[gid] = y2; dsc[gid] = prob;

  // zero the output row; scan_kernel scatters kept rows afterwards
  out[gid * 5 + 0] = 0.0f;
  out[gid * 5 + 1] = 0.0f;
  out[gid * 5 + 2] = 0.0f;
  out[gid * 5 + 3] = 0.0f;
  out[gid * 5 + 4] = 0.0f;

  // Only boxes with score > FINAL_TH can affect the output (suppression only
  // flows downward in score order, and only >FINAL_TH rows are exposed).
  if (prob > FINAL_TH) {
    unsigned int pos = atomicAdd(Mc, 1u);
    ckey[pos] = ((unsigned long long)__float_as_uint(prob) << 32) |
                (unsigned int)(~(unsigned int)gid);
  }
}

// ---------------------------------------------------------------- rank ------
// Count-rank with 8-way key-range split; packed atomicAdd join.
__global__ void __launch_bounds__(256)
rank_kernel(const unsigned long long* __restrict__ ckey,
            const unsigned int* __restrict__ Mc,
            const float* __restrict__ dx1, const float* __restrict__ dy1,
            const float* __restrict__ dx2, const float* __restrict__ dy2,
            float* __restrict__ sx1, float* __restrict__ sy1,
            float* __restrict__ sx2, float* __restrict__ sy2,
            unsigned int* __restrict__ sorig,
            unsigned int* __restrict__ rank32) {
  __shared__ unsigned long long tile[256];
  const unsigned int M = *Mc;
  if (blockIdx.x * 256u >= M) return;          // uniform per block
  const int t = (int)threadIdx.x;
  const int p = (int)blockIdx.x * 256 + t;
  unsigned long long mykey = (p < (int)M) ? ckey[p] : 0ull;
  const int S  = (int)((M + NSLICE - 1) / NSLICE);
  const int lo = (int)blockIdx.y * S;
  const int hi = min((int)M, lo + S);
  int partial = 0;
  const int nt = (hi > lo) ? ((hi - lo + 255) >> 8) : 0;
  for (int ti = 0; ti < nt; ++ti) {
    int j = lo + ti * 256 + t;
    tile[t] = (j < hi) ? ckey[j] : 0ull;       // 0 never > any real key
    __syncthreads();
#pragma unroll 8
    for (int q = 0; q < 256; ++q) partial += (tile[q] > mykey) ? 1 : 0;
    __syncthreads();
  }
  if (p < (int)M) {
    unsigned int pack = (unsigned int)partial | (1u << 24);
    unsigned int old  = atomicAdd(&rank32[p], pack);
    unsigned int newv = old + pack;
    if ((newv >> 24) == NSLICE) {              // last slice to land scatters
      int r = (int)(newv & 0xFFFFFF);
      unsigned int orig = ~(unsigned int)(mykey & 0xffffffffull);
      sx1[r] = dx1[orig];
      sy1[r] = dy1[orig];
      sx2[r] = dx2[orig];
      sy2[r] = dy2[orig];
      sorig[r] = orig;
    }
  }
}

// ---------------------------------------------------------------- pairs -----
// Sparse suppression structure:
//   diag[r]  = in-word bits (cw == rw, cols > r)
//   offd[r]  = bits vs next word (cw == rw+1)
//   CSR rows: rlJw/rlBits[rowbase(r) + k], k < cnt[r], for cw >= rw+2, bits!=0
// 1024-thread blocks: 16 waves = 16 col-words per (row-word) y.
__global__ void __launch_bounds__(1024)
pairs_kernel(const float* __restrict__ sx1, const float* __restrict__ sy1,
             const float* __restrict__ sx2, const float* __restrict__ sy2,
             const unsigned int* __restrict__ Mc,
             unsigned long long* __restrict__ diag,
             unsigned long long* __restrict__ offd,
             unsigned int* __restrict__ cnt,
             unsigned short* __restrict__ rlJw,
             unsigned long long* __restrict__ rlBits) {
#pragma clang fp contract(off)
  const int M = (int)*Mc;
  const int W = (M + 63) >> 6;
  const int rw = (int)blockIdx.y;
  const int cwg = (int)blockIdx.x << 4;
  if (rw >= W || cwg >= W || cwg + 15 < rw) return;

  const int t = (int)threadIdx.x;
  const int g = t >> 6, l = t & 63;
  const int cw = cwg + g;

  __shared__ float cx1[1024], cy1[1024], cx2[1024], cy2[1024], car[1024];
  {
    int c = (cw << 6) + l;
    if (cw < W && c < M) {
      float a = sx1[c], b = sy1[c], d = sx2[c], e = sy2[c];
      cx1[t] = a; cy1[t] = b; cx2[t] = d; cy2[t] = e;
      car[t] = (d - a + 1.0f) * (e - b + 1.0f);
    }
  }
  __syncthreads();
  if (cw >= W || cw < rw) return;

  const int r = (rw << 6) + l;
  unsigned long long bits = 0ull;
  if (r < M) {
    float ax1 = sx1[r], ay1 = sy1[r], ax2 = sx2[r], ay2 = sy2[r];
    float aarea = (ax2 - ax1 + 1.0f) * (ay2 - ay1 + 1.0f);
    const int cmax = min(64, M - (cw << 6));
    const int sb = g << 6;
    for (int cc = 0; cc < cmax; ++cc) {
      int cg = (cw << 6) + cc;
      if (cg > r) {
        float xx1 = fmaxf(ax1, cx1[sb + cc]);
        float yy1 = fmaxf(ay1, cy1[sb + cc]);
        float xx2 = fminf(ax2, cx2[sb + cc]);
        float yy2 = fminf(ay2, cy2[sb + cc]);
        float ww = fmaxf(xx2 - xx1 + 1.0f, 0.0f);
        float hh = fmaxf(yy2 - yy1 + 1.0f, 0.0f);
        float inter = ww * hh;
        float iou = inter / (aarea + car[sb + cc] - inter);
        if (iou > NMS_TH) bits |= (1ull << cc);
      }
    }
  }
  if (cw == rw)            diag[r] = bits;
  else if (cw == rw + 1)   offd[r] = bits;
  else if (bits != 0ull) {
    unsigned k = atomicAdd(&cnt[r], 1u);
    unsigned b = rowbase_u((unsigned)r) + k;   // capacity 342-rw >= possible
    rlJw[b]   = (unsigned short)cw;
    rlBits[b] = bits;
  }
}

// ---------------------------------------------------------------- scan ------
// Single-block greedy scan over the SPARSE structure. Wave 0 scans word-by-
// word (diag) and carries the w->w+1 push in registers (offd + shfl-OR);
// waves 1-15 = 960 lanes apply CSR entries (jw >= w+2) with arithmetic
// addresses, 3-deep predicated prefetch. ONE barrier per step.
__global__ void __launch_bounds__(1024)
scan_kernel(const unsigned long long* __restrict__ diag,
            const unsigned long long* __restrict__ offd,
            const unsigned int* __restrict__ cnt,
            const unsigned short* __restrict__ rlJw,
            const unsigned long long* __restrict__ rlBits,
            const unsigned int* __restrict__ sorig,
            const unsigned int* __restrict__ Mc,
            const float* __restrict__ dx1, const float* __restrict__ dy1,
            const float* __restrict__ dx2, const float* __restrict__ dy2,
            const float* __restrict__ dsc,
            float* __restrict__ out) {
  __shared__ unsigned long long sup[W_MAX];
  __shared__ unsigned long long kmls[W_MAX];
  const int t = (int)threadIdx.x;
  const int g = t >> 6, l = t & 63;
  const int M = (int)*Mc;
  const int W = (M + 63) >> 6;

  for (int i = t; i < W_MAX; i += 1024) { sup[i] = 0ull; kmls[i] = 0ull; }
  block_bar();

  if (g == 0) {
    // -------- scanner wave --------
    unsigned long long rb   = diag[l];                       // word0 in-word
    unsigned long long pv   = (W > 1) ? offd[l] : 0ull;      // word0 -> word1
    unsigned long long inln = 0ull;                          // carried push
    for (int w = 0; w < W; ++w) {
      const int base = w << 6;
      unsigned long long supw = sup[w];
      unsigned long long rowbits = rb;
      unsigned long long pvc = pv;
      {   // prefetch next step's two blocks
        int rn = base + 64 + l;
        rb = (w + 1 < W) ? diag[rn] : 0ull;
        pv = (w + 2 < W) ? offd[rn] : 0ull;
      }
      unsigned long long nz = __ballot(rowbits != 0ull);
      const int n = min(64, M - base);
      unsigned long long wordmask = (n >= 64) ? ~0ull : ((1ull << n) - 1ull);
      unsigned long long pend = (~(supw | inln)) & wordmask;
      unsigned long long kept = 0ull;
      unsigned long long act = pend & nz;
      while (act) {                       // iterations = #kept rows w/ bits
        int i = __builtin_ctzll(act);
        unsigned long long upto = (2ull << i) - 1ull;  // bits [0..i]
        kept |= pend & upto;
        unsigned long long ri = __shfl(rowbits, i);
        pend &= ~upto;
        pend &= ~ri;
        act = pend & nz;
      }
      kept |= pend;
      if (l == 0) kmls[w] = kept;
      // inline push w -> w+1: OR of pvc over kept lanes (in-register)
      unsigned long long x = ((kept >> l) & 1ull) ? pvc : 0ull;
#pragma unroll
      for (int off = 32; off; off >>= 1) x |= __shfl_xor(x, off);
      inln = x;
      block_bar();
    }
  } else {
    // -------- pusher lanes: 960 = 64 rows x 15 slots --------
    const int p = (g - 1) * 64 + l;
    const int jrow = p / 15;             // row within word, 0..63
    const int sub  = p % 15;             // CSR slot 0..14
    unsigned c0, c1, c2, c3;             // cnt pipeline (w .. w+3)
    unsigned long long b0, b1, b2;       // bits pipeline (w .. w+2)
    unsigned j0, j1, j2;                 // jw pipeline
    {   // prologue (unconditional clamped loads; waste only, predicated later)
      c0 = cnt[jrow];
      c1 = (1 < W) ? cnt[64 + jrow] : 0u;
      c2 = (2 < W) ? cnt[128 + jrow] : 0u;
      c3 = (3 < W) ? cnt[192 + jrow] : 0u;
      unsigned i;
      i = rowbase_u((unsigned)jrow) + sub;        if (i >= TOT_ENT) i = 0;
      b0 = rlBits[i]; j0 = rlJw[i];
      i = rowbase_u((unsigned)(64 + jrow)) + sub; if (i >= TOT_ENT) i = 0;
      b1 = rlBits[i]; j1 = rlJw[i];
      i = rowbase_u((unsigned)(128 + jrow)) + sub; if (i >= TOT_ENT) i = 0;
      b2 = rlBits[i]; j2 = rlJw[i];
    }
    for (int w = 0; w < W; ++w) {
      block_bar();
      const unsigned long long km = kmls[w];
      if ((km >> jrow) & 1ull) {
        if (sub < (int)c0) atomicOr(&sup[j0], b0);
        if (c0 > 15u) {                  // rare high-degree tail
          unsigned rb_ = rowbase_u((unsigned)(w * 64 + jrow));
          for (int k = sub + 15; k < (int)c0; k += 15) {
            unsigned ii = rb_ + k;
            atomicOr(&sup[rlJw[ii]], rlBits[ii]);
          }
        }
      }
      // rotate pipelines
      c0 = c1; c1 = c2; c2 = c3;
      b0 = b1; j0 = j1; b1 = b2; j1 = j2;
      // issue: cnt for w+4; bits/jw for w+3 predicated by its cnt (c2)
      {
        int w4 = w + 4;
        c3 = (w4 < W) ? cnt[w4 * 64 + jrow] : 0u;
        int w3 = w + 3;
        bool ld = (w3 < W) && (sub < (int)c2);
        unsigned i = ld ? (rowbase_u((unsigned)(w3 * 64 + jrow)) + sub) : 0u;
        if (i >= TOT_ENT) i = 0;
        b2 = ld ? rlBits[i] : 0ull;
        j2 = ld ? (unsigned)rlJw[i] : 0u;
      }
    }
  }
  block_bar();

  // scatter kept rows into the (pre-zeroed) output
  for (int i = t; i < (W << 6); i += 1024) {
    if ((kmls[i >> 6] >> (i & 63)) & 1ull) {
      unsigned int orig = sorig[i];
      out[(size_t)orig * 5 + 0] = dx1[orig];
      out[(size_t)orig * 5 + 1] = dy1[orig];
      out[(size_t)orig * 5 + 2] = dx2[orig];
      out[(size_t)orig * 5 + 3] = dy2[orig];
      out[(size_t)orig * 5 + 4] = dsc[orig];
    }
  }
}

// ------------------------------------------------- fallback NMS (tiny ws) ---
__global__ void __launch_bounds__(1024)
nms_kernel(const float* __restrict__ sx1, const float* __restrict__ sy1,
           const float* __restrict__ sx2, const float* __restrict__ sy2,
           const unsigned int* __restrict__ sorig,
           const unsigned int* __restrict__ Mc,
           unsigned int* __restrict__ keepflag) {
#pragma clang fp contract(off)
  __shared__ unsigned long long sup[W_MAX];
  __shared__ unsigned long long inrow[64];
  __shared__ float wx1[64], wy1[64], wx2[64], wy2[64], warea[64];
  __shared__ unsigned long long keptmask_sh;

  const int t = (int)threadIdx.x;
  const int M = (int)*Mc;
  const int W = (M + 63) >> 6;

  for (int i = t; i < W_MAX; i += 1024) sup[i] = 0ull;
  __syncthreads();

  for (int w = 0; w < W; ++w) {
    const int base = w << 6;
    const int n = min(64, M - base);
    if (t < 64) {
      if (t < n) {
        float a = sx1[base + t], b = sy1[base + t];
        float c = sx2[base + t], d = sy2[base + t];
        wx1[t] = a; wy1[t] = b; wx2[t] = c; wy2[t] = d;
        warea[t] = (c - a + 1.0f) * (d - b + 1.0f);
      }
    } else if (t < 128) {
      inrow[t - 64] = 0ull;
    }
    __syncthreads();
    {
      int r = t & 63, seg = t >> 6;
      unsigned long long bits = 0ull;
      if (r < n) {
        float ax1 = wx1[r], ay1 = wy1[r], ax2 = wx2[r], ay2 = wy2[r];
        float aarea = warea[r];
        for (int c = seg * 4; c < seg * 4 + 4; ++c) {
          if (c > r && c < n) {
            float xx1 = fmaxf(ax1, wx1[c]);
            float yy1 = fmaxf(ay1, wy1[c]);
            float xx2 = fminf(ax2, wx2[c]);
            float yy2 = fminf(ay2, wy2[c]);
            float ww = fmaxf(xx2 - xx1 + 1.0f, 0.0f);
            float hh = fmaxf(yy2 - yy1 + 1.0f, 0.0f);
            float inter = ww * hh;
            float iou = inter / (aarea + warea[c] - inter);
            if (iou > NMS_TH) bits |= (1ull << c);
          }
        }
      }
      if (bits) atomicOr(&inrow[r], bits);
    }
    __syncthreads();
    if (t < 64) {
      unsigned long long wordmask = (n >= 64) ? ~0ull : ((1ull << n) - 1ull);
      unsigned long long pending = (~sup[w]) & wordmask;
      unsigned long long kept = 0ull;
      while (pending) {
        int i = __builtin_ctzll(pending);
        kept |= (1ull << i);
        pending &= ~(inrow[i] | (1ull << i));
      }
      if (t == 0) keptmask_sh = kept;
      if (t < n && ((kept >> t) & 1ull)) keepflag[sorig[base + t]] = 1u;
    }
    __syncthreads();
    unsigned long long km = keptmask_sh;
    if (km) {
      int wid = t >> 6, lane = t & 63;
      for (int jw = w + 1 + wid; (jw << 6) < M; jw += 16) {
        int j = (jw << 6) + lane;
        bool supj = false;
        if (j < M) {
          float jx1 = sx1[j], jy1 = sy1[j], jx2 = sx2[j], jy2 = sy2[j];
          float jarea = (jx2 - jx1 + 1.0f) * (jy2 - jy1 + 1.0f);
          unsigned long long mm = km;
          while (mm) {
            int r = __builtin_ctzll(mm);
            mm &= mm - 1ull;
            float xx1 = fmaxf(wx1[r], jx1);
            float yy1 = fmaxf(wy1[r], jy1);
            float xx2 = fminf(wx2[r], jx2);
            float yy2 = fminf(wy2[r], jy2);
            float ww = fmaxf(xx2 - xx1 + 1.0f, 0.0f);
            float hh = fmaxf(yy2 - yy1 + 1.0f, 0.0f);
            float inter = ww * hh;
            float iou = inter / (warea[r] + jarea - inter);
            if (iou > NMS_TH) { supj = true; break; }
          }
        }
        unsigned long long bal = __ballot(supj);
        if (lane == 0 && bal) atomicOr(&sup[jw], bal);
      }
    }
    __syncthreads();
  }
}

// ---------------------------------------------------------------- output ----
// (fallback path only)
__global__ void output_kernel(const float* __restrict__ dx1, const float* __restrict__ dy1,
                              const float* __restrict__ dx2, const float* __restrict__ dy2,
                              const float* __restrict__ dsc,
                              const unsigned int* __restrict__ keepflag,
                              float* __restrict__ out) {
#pragma clang fp contract(off)
  int gid = blockIdx.x * blockDim.x + threadIdx.x;
  if (gid >= N_TOTAL) return;
  float f = keepflag[gid] ? 1.0f : 0.0f;
  out[gid * 5 + 0] = dx1[gid] * f;
  out[gid * 5 + 1] = dy1[gid] * f;
  out[gid * 5 + 2] = dx2[gid] * f;
  out[gid * 5 + 3] = dy2[gid] * f;
  out[gid * 5 + 4] = dsc[gid] * f;
}

// ---------------------------------------------------------------- launch ----
extern "C" void kernel_launch(void* const* d_in, const int* in_sizes, int n_in,
                              void* d_out, int out_size, void* d_ws, size_t ws_size,
                              hipStream_t stream) {
  (void)in_sizes; (void)n_in; (void)out_size;

  Inputs in;
  for (int i = 0; i < 6; ++i) {
    in.cls[i] = (const float*)d_in[2 * i];
    in.reg[i] = (const float*)d_in[2 * i + 1];
  }

  char* ws = (char*)d_ws;
  size_t o = 0;
  float* dx1 = (float*)(ws + o); o += (size_t)NA * 4;
  float* dy1 = (float*)(ws + o); o += (size_t)NA * 4;
  float* dx2 = (float*)(ws + o); o += (size_t)NA * 4;
  float* dy2 = (float*)(ws + o); o += (size_t)NA * 4;
  float* dsc = (float*)(ws + o); o += (size_t)NA * 4;
  unsigned long long* ckey = (unsigned long long*)(ws + o); o += (size_t)NA * 8;
  float* sx1 = (float*)(ws + o); o += (size_t)NA * 4;
  float* sy1 = (float*)(ws + o); o += (size_t)NA * 4;
  float* sx2 = (float*)(ws + o); o += (size_t)NA * 4;
  float* sy2 = (float*)(ws + o); o += (size_t)NA * 4;
  unsigned int* sorig = (unsigned int*)(ws + o); o += (size_t)NA * 4;
  unsigned int* keepflag = (unsigned int*)(ws + o); o += (size_t)NA * 4;
  unsigned int* rank32 = (unsigned int*)(ws + o); o += (size_t)NA * 4;
  unsigned int* cnt = (unsigned int*)(ws + o); o += (size_t)NA * 4;
  unsigned int* Mc = (unsigned int*)(ws + o); o += 64;
  o = (o + 511) & ~(size_t)511;
  unsigned long long* diag = (unsigned long long*)(ws + o); o += (size_t)NA * 8;
  unsigned long long* offd = (unsigned long long*)(ws + o); o += (size_t)NA * 8;
  unsigned long long* rlBits = (unsigned long long*)(ws + o); o += (size_t)TOT_ENT * 8;
  unsigned short* rlJw = (unsigned short*)(ws + o); o += (size_t)TOT_ENT * 2;
  size_t need = o;                            // ~40 MiB
  const bool fast = (need <= ws_size);        // ws_size constant -> graph-safe

  const int nb = (N_TOTAL + 255) / 256;  // 86

  if (fast) {
    (void)hipMemsetAsync((void*)Mc, 0, 64, stream);
    decode_kernel<<<nb, 256, 0, stream>>>(in, dx1, dy1, dx2, dy2, dsc, ckey, Mc,
                                          rank32, cnt, (float*)d_out);
    rank_kernel<<<dim3(nb, NSLICE), 256, 0, stream>>>(ckey, Mc, dx1, dy1, dx2, dy2,
                                                      sx1, sy1, sx2, sy2, sorig,
                                                      rank32);
    pairs_kernel<<<dim3(22, W_MAX), 1024, 0, stream>>>(sx1, sy1, sx2, sy2, Mc,
                                                       diag, offd, cnt, rlJw, rlBits);
    scan_kernel<<<1, 1024, 0, stream>>>(diag, offd, cnt, rlJw, rlBits, sorig, Mc,
                                        dx1, dy1, dx2, dy2, dsc, (float*)d_out);
  } else {
    // fallback: zero keepflag + rank32 + cnt + Mc (contiguous)
    (void)hipMemsetAsync((void*)keepflag, 0, (size_t)NA * 12 + 64, stream);
    decode_kernel<<<nb, 256, 0, stream>>>(in, dx1, dy1, dx2, dy2, dsc, ckey, Mc,
                                          rank32, cnt, (float*)d_out);
    rank_kernel<<<dim3(nb, NSLICE), 256, 0, stream>>>(ckey, Mc, dx1, dy1, dx2, dy2,
                                                      sx1, sy1, sx2, sy2, sorig,
                                                      rank32);
    nms_kernel<<<1, 1024, 0, stream>>>(sx1, sy1, sx2, sy2, sorig, Mc, keepflag);
    output_kernel<<<nb, 256, 0, stream>>>(dx1, dy1, dx2, dy2, dsc, keepflag,
                                          (float*)d_out);
  }
}